// Round 1
// baseline (610.111 us; speedup 1.0000x reference)
//
#include <hip/hip_runtime.h>
#include <math.h>

// ---------------------------------------------------------------------------
// Problem constants
//   x: (B=2, C=64, H=128, W=128) fp32, HW = 16384 tokens per batch
//   spatial mamba: d_model=64, d_inner=128, dt_rank=4, d_state=16, L=16384
//   spectral mamba: per-pixel sequence of TOKEN=8 over channel groups of 8,
//                   d_model=8, d_inner=16, dt_rank=1, d_state=16
// ---------------------------------------------------------------------------

#define NB 2
#define NC 64
#define HW_ 16384
#define SCH 256          // spatial scan chunks per batch
#define SLC 64           // tokens per chunk (16384/256)

__device__ __forceinline__ float sigmoidf_(float v) { return 1.f / (1.f + __expf(-v)); }
__device__ __forceinline__ float siluf_(float v)    { return v * sigmoidf_(v); }
__device__ __forceinline__ float softplusf_(float v) {
    return v > 0.f ? v + log1pf(__expf(-v)) : log1pf(__expf(v));
}

// ---------------------------------------------------------------------------
// K1: spatial in_proj + depthwise causal conv + silu + x-proj(B,C,dt) + delta
// grid 512 (= 2 b * 256 tiles of 64 tokens), block 256
// LDS: pre-activations region reused for post-conv tile (phased, barriered)
// ---------------------------------------------------------------------------
#define K1_XS_OFF 8576       // floats; pre/xcl region is [0, 8576)
#define K1_XS_STR 68         // x tile row stride (4-aligned, bank-rotating)
#define K1_XCL_STR 132       // conv-output tile row stride

__global__ __launch_bounds__(256) void k1_spatial_pre(
    const float* __restrict__ x, const float* __restrict__ in_w,
    const float* __restrict__ conv_w, const float* __restrict__ conv_b,
    const float* __restrict__ xp_w, const float* __restrict__ dt_w,
    const float* __restrict__ dt_b,
    float* __restrict__ xc_g, float* __restrict__ sz_g,
    float* __restrict__ delta_g, float* __restrict__ Bm_g, float* __restrict__ Cm_g)
{
    __shared__ float smem[13132];   // 8576 (pre/xcl) + 67*68 (x tile)
    __shared__ float dtl[256];      // dt-projection per (token, r)
    const int tid = threadIdx.x;
    const int b   = blockIdx.x >> 8;
    const int l0  = (blockIdx.x & 255) << 6;

    // ---- Phase A: load x tile, tokens l0-3 .. l0+63, layout [tok][c] ----
    for (int i = tid; i < 67 * 64; i += 256) {
        int c = i / 67;
        int tok = i - c * 67;
        int l = l0 + tok - 3;
        float v = (l >= 0) ? x[((size_t)b * NC + c) * HW_ + l] : 0.f;
        smem[K1_XS_OFF + tok * K1_XS_STR + c] = v;
    }
    __syncthreads();

    // ---- Phase B: in_proj (256x64 matvec per token), weights in VGPRs ----
    {
        const int e = tid & 127;
        const int half = tid >> 7;
        float w[64];
        #pragma unroll
        for (int q = 0; q < 16; ++q) {
            float4 wv = *(const float4*)(in_w + e * 64 + q * 4);
            w[q*4] = wv.x; w[q*4+1] = wv.y; w[q*4+2] = wv.z; w[q*4+3] = wv.w;
        }
        int t0 = half ? 34 : 0, t1 = half ? 67 : 34;
        for (int tok = t0; tok < t1; ++tok) {
            const float4* xr = (const float4*)(smem + K1_XS_OFF + tok * K1_XS_STR);
            float acc = 0.f;
            #pragma unroll
            for (int q = 0; q < 16; ++q) {
                float4 xv = xr[q];
                acc += w[q*4]*xv.x + w[q*4+1]*xv.y + w[q*4+2]*xv.z + w[q*4+3]*xv.w;
            }
            smem[tok * 128 + e] = acc;      // pre-conv activation
        }
        #pragma unroll
        for (int q = 0; q < 16; ++q) {
            float4 wv = *(const float4*)(in_w + (128 + e) * 64 + q * 4);
            w[q*4] = wv.x; w[q*4+1] = wv.y; w[q*4+2] = wv.z; w[q*4+3] = wv.w;
        }
        int z0 = half * 32;
        for (int tok = z0; tok < z0 + 32; ++tok) {
            const float4* xr = (const float4*)(smem + K1_XS_OFF + (tok + 3) * K1_XS_STR);
            float acc = 0.f;
            #pragma unroll
            for (int q = 0; q < 16; ++q) {
                float4 xv = xr[q];
                acc += w[q*4]*xv.x + w[q*4+1]*xv.y + w[q*4+2]*xv.z + w[q*4+3]*xv.w;
            }
            sz_g[((size_t)(b * HW_ + l0 + tok)) * 128 + e] = siluf_(acc);  // silu(z)
        }
    }
    __syncthreads();

    // ---- Phase C: depthwise causal conv (k=4) + bias + silu ----
    {
        const int e = tid & 127;
        float cw0 = conv_w[e*4], cw1 = conv_w[e*4+1], cw2 = conv_w[e*4+2], cw3 = conv_w[e*4+3];
        float cb = conv_b[e];
        float r[32];
        #pragma unroll
        for (int k = 0; k < 32; ++k) {
            int tok = (tid + k * 256) >> 7;
            float v = cb + cw0 * smem[(tok+0)*128 + e] + cw1 * smem[(tok+1)*128 + e]
                         + cw2 * smem[(tok+2)*128 + e] + cw3 * smem[(tok+3)*128 + e];
            v = siluf_(v);
            r[k] = v;
            xc_g[((size_t)(b * HW_ + l0 + tok)) * 128 + e] = v;
        }
        __syncthreads();
        #pragma unroll
        for (int k = 0; k < 32; ++k) {
            int tok = (tid + k * 256) >> 7;
            smem[tok * K1_XCL_STR + e] = r[k];   // overwrite pre region (barriered)
        }
    }
    __syncthreads();

    // ---- Phase D1: B (rows 4..19) and C (rows 20..35) projections ----
    for (int i = tid; i < 64 * 32; i += 256) {
        int tok = i >> 5;
        int f = i & 31;
        const float4* xr = (const float4*)(smem + tok * K1_XCL_STR);
        const float4* wr = (const float4*)(xp_w + (4 + f) * 128);
        float acc = 0.f;
        #pragma unroll
        for (int q = 0; q < 32; ++q) {
            float4 a = xr[q], w4 = wr[q];
            acc += a.x*w4.x + a.y*w4.y + a.z*w4.z + a.w*w4.w;
        }
        size_t row = (size_t)(b * HW_ + l0 + tok);
        if (f < 16) Bm_g[row * 16 + f] = acc;
        else        Cm_g[row * 16 + (f - 16)] = acc;
    }
    // ---- Phase D2: dt projection (rows 0..3), one (token,r) per thread ----
    {
        int tok = tid >> 2;
        int rr = tid & 3;
        const float4* xr = (const float4*)(smem + tok * K1_XCL_STR);
        const float4* wr = (const float4*)(xp_w + rr * 128);
        float acc = 0.f;
        #pragma unroll
        for (int q = 0; q < 32; ++q) {
            float4 a = xr[q], w4 = wr[q];
            acc += a.x*w4.x + a.y*w4.y + a.z*w4.z + a.w*w4.w;
        }
        dtl[tid] = acc;
    }
    __syncthreads();
    // ---- Phase D3: delta = softplus(dt @ dt_w^T + dt_b) ----
    {
        const int e = tid & 127;
        float w0 = dt_w[e*4], w1 = dt_w[e*4+1], w2 = dt_w[e*4+2], w3 = dt_w[e*4+3];
        float bb = dt_b[e];
        #pragma unroll
        for (int k = 0; k < 32; ++k) {
            int tok = (tid + k * 256) >> 7;
            float4 dv = *(const float4*)(dtl + tok * 4);
            float v = bb + w0*dv.x + w1*dv.y + w2*dv.z + w3*dv.w;
            delta_g[((size_t)(b * HW_ + l0 + tok)) * 128 + e] = softplusf_(v);
        }
    }
}

// ---------------------------------------------------------------------------
// K2: spatial scan pass 1 — per-chunk summaries (cumulative dA product, local h)
// grid 512 (b*256 chunks), block 256: thread = (e, n-half), 8 states each
// ---------------------------------------------------------------------------
__global__ __launch_bounds__(256) void k2_scan1(
    const float* __restrict__ delta_g, const float* __restrict__ xc_g,
    const float* __restrict__ Bm_g, const float* __restrict__ A_log,
    float* __restrict__ cumA_g, float* __restrict__ hsum_g)
{
    const int tid = threadIdx.x;
    const int b = blockIdx.x >> 8;
    const int ch = blockIdx.x & 255;
    const int e = tid >> 1;
    const int n0 = (tid & 1) * 8;
    float A[8];
    #pragma unroll
    for (int j = 0; j < 8; ++j) A[j] = -__expf(A_log[e * 16 + n0 + j]);
    float h[8], cA[8];
    #pragma unroll
    for (int j = 0; j < 8; ++j) { h[j] = 0.f; cA[j] = 1.f; }
    const size_t rowbase = (size_t)b * HW_ + ch * SLC;
    for (int t = 0; t < SLC; ++t) {
        size_t row = rowbase + t;
        float d = delta_g[row * 128 + e];
        float u = xc_g[row * 128 + e];
        float4 b0 = *(const float4*)(Bm_g + row * 16 + n0);
        float4 b1 = *(const float4*)(Bm_g + row * 16 + n0 + 4);
        float Bv[8]; *(float4*)(Bv) = b0; *(float4*)(Bv + 4) = b1;
        float du = d * u;
        #pragma unroll
        for (int j = 0; j < 8; ++j) {
            float dA = __expf(d * A[j]);
            h[j] = h[j] * dA + du * Bv[j];
            cA[j] *= dA;
        }
    }
    size_t so = ((size_t)(b * SCH + ch)) * 2048 + tid * 8;
    #pragma unroll
    for (int j = 0; j < 8; ++j) { cumA_g[so + j] = cA[j]; hsum_g[so + j] = h[j]; }
}

// ---------------------------------------------------------------------------
// K3: cross-chunk exclusive combine (4096 independent streams, 256 steps)
// ---------------------------------------------------------------------------
__global__ __launch_bounds__(256) void k3_combine(
    const float* __restrict__ cumA_g, const float* __restrict__ hsum_g,
    float* __restrict__ Hin_g)
{
    int gid = blockIdx.x * 256 + threadIdx.x;     // 0..4095
    int b = gid >> 11;
    int en = gid & 2047;
    float st = 0.f;
    size_t o = (size_t)b * SCH * 2048 + en;
    #pragma unroll 4
    for (int ch = 0; ch < SCH; ++ch) {
        Hin_g[o] = st;
        st = st * cumA_g[o] + hsum_g[o];
        o += 2048;
    }
}

// ---------------------------------------------------------------------------
// K4: spatial scan pass 2 + y gating + out_proj + NCHW store + GN partials
// grid 512, block 256
// ---------------------------------------------------------------------------
__global__ __launch_bounds__(256) void k4_scan2(
    const float* __restrict__ delta_g, const float* __restrict__ xc_g,
    const float* __restrict__ sz_g, const float* __restrict__ Bm_g,
    const float* __restrict__ Cm_g, const float* __restrict__ A_log,
    const float* __restrict__ Dp, const float* __restrict__ Hin_g,
    const float* __restrict__ out_w,
    float* __restrict__ spa_raw, float* __restrict__ part_spa)
{
    __shared__ float ytile[SLC * 128];   // y'(t,e)
    __shared__ float otile[64 * 65];     // out(c,t), padded
    __shared__ float wred[32];
    const int tid = threadIdx.x;
    const int b = blockIdx.x >> 8;
    const int ch = blockIdx.x & 255;
    const int e = tid >> 1;
    const int nh = tid & 1;
    const int n0 = nh * 8;
    float A[8];
    #pragma unroll
    for (int j = 0; j < 8; ++j) A[j] = -__expf(A_log[e * 16 + n0 + j]);
    float Dv = Dp[e];
    float h[8];
    size_t so = ((size_t)(b * SCH + ch)) * 2048 + tid * 8;
    #pragma unroll
    for (int j = 0; j < 8; ++j) h[j] = Hin_g[so + j];
    const size_t rowbase = (size_t)b * HW_ + ch * SLC;
    for (int t = 0; t < SLC; ++t) {
        size_t row = rowbase + t;
        float d = delta_g[row * 128 + e];
        float u = xc_g[row * 128 + e];
        float4 b0 = *(const float4*)(Bm_g + row * 16 + n0);
        float4 b1 = *(const float4*)(Bm_g + row * 16 + n0 + 4);
        float4 c0 = *(const float4*)(Cm_g + row * 16 + n0);
        float4 c1 = *(const float4*)(Cm_g + row * 16 + n0 + 4);
        float Bv[8]; *(float4*)(Bv) = b0; *(float4*)(Bv + 4) = b1;
        float Cv[8]; *(float4*)(Cv) = c0; *(float4*)(Cv + 4) = c1;
        float du = d * u;
        float y = 0.f;
        #pragma unroll
        for (int j = 0; j < 8; ++j) {
            float dA = __expf(d * A[j]);
            h[j] = h[j] * dA + du * Bv[j];
            y += h[j] * Cv[j];
        }
        y += __shfl_xor(y, 1, 64);          // combine both n-halves
        if (nh == 0) {
            float szv = sz_g[row * 128 + e];
            ytile[t * 128 + e] = (y + u * Dv) * szv;
        }
    }
    __syncthreads();
    // out_proj: out(c,t) = sum_e out_w[c][e] * y'(t,e)
    for (int i = tid; i < 64 * SLC; i += 256) {
        int c = i & 63, t = i >> 6;
        const float4* wr = (const float4*)(out_w + c * 128);
        const float4* yr = (const float4*)(ytile + t * 128);
        float acc = 0.f;
        #pragma unroll
        for (int q = 0; q < 32; ++q) {
            float4 w4 = wr[q], yv4 = yr[q];
            acc += w4.x*yv4.x + w4.y*yv4.y + w4.z*yv4.z + w4.w*yv4.w;
        }
        otile[c * 65 + t] = acc;
    }
    __syncthreads();
    for (int i = tid; i < 64 * SLC; i += 256) {
        int c = i >> 6, t = i & 63;
        spa_raw[((size_t)b * NC + c) * HW_ + ch * SLC + t] = otile[c * 65 + t];
    }
    // GroupNorm partial sums (4 groups of 16 channels)
    float s[4], s2[4];
    #pragma unroll
    for (int g = 0; g < 4; ++g) {
        float a = 0.f, a2 = 0.f;
        for (int i = tid; i < 1024; i += 256) {
            int c = 16 * g + (i >> 6), t = i & 63;
            float v = otile[c * 65 + t];
            a += v; a2 += v * v;
        }
        s[g] = a; s2[g] = a2;
    }
    #pragma unroll
    for (int g = 0; g < 4; ++g) {
        #pragma unroll
        for (int o = 1; o < 64; o <<= 1) {
            s[g]  += __shfl_xor(s[g], o, 64);
            s2[g] += __shfl_xor(s2[g], o, 64);
        }
    }
    if ((tid & 63) == 0) {
        int w = tid >> 6;
        #pragma unroll
        for (int g = 0; g < 4; ++g) { wred[w*8 + g*2] = s[g]; wred[w*8 + g*2 + 1] = s2[g]; }
    }
    __syncthreads();
    if (tid < 8)
        part_spa[blockIdx.x * 8 + tid] = wred[tid] + wred[8+tid] + wred[16+tid] + wred[24+tid];
}

// ---------------------------------------------------------------------------
// K5: whole spectral mamba fused. 16 lanes per pixel-sequence, 16 seq/block.
// grid 2048 (b*1024 groups of 16 pixels), block 256
// ---------------------------------------------------------------------------
__global__ __launch_bounds__(256) void k5_spectral(
    const float* __restrict__ x, const float* __restrict__ in_w,
    const float* __restrict__ conv_w, const float* __restrict__ conv_b,
    const float* __restrict__ xp_w, const float* __restrict__ dt_w,
    const float* __restrict__ dt_b, const float* __restrict__ A_log,
    const float* __restrict__ Dp, const float* __restrict__ out_w,
    float* __restrict__ spe_raw, float* __restrict__ part_spe)
{
    __shared__ float xin[16 * 65];    // [seq][c]
    __shared__ float xcs[16 * 132];   // [seq][t*16+e]
    __shared__ float Bs[16 * 132];
    __shared__ float Cs[16 * 132];
    __shared__ float ys[16 * 136];    // [seq][t*17+e]
    __shared__ float outs[64 * 17];   // [c][seq]
    __shared__ float wred[32];
    const int tid = threadIdx.x;
    const int b = blockIdx.x >> 10;
    const int hw0 = (blockIdx.x & 1023) << 4;

    for (int i = tid; i < 1024; i += 256) {
        int c = i >> 4, j = i & 15;
        xin[j * 65 + c] = x[((size_t)b * NC + c) * HW_ + hw0 + j];
    }
    __syncthreads();

    const int s = tid >> 4;     // sequence in block
    const int l = tid & 15;     // inner-channel e (and state-index n role)
    float wi0[8], wi1[8];
    #pragma unroll
    for (int c = 0; c < 8; ++c) { wi0[c] = in_w[l*8 + c]; wi1[c] = in_w[(l+16)*8 + c]; }
    float cw0 = conv_w[l*4], cw1 = conv_w[l*4+1], cw2 = conv_w[l*4+2], cw3 = conv_w[l*4+3];
    float cb = conv_b[l];
    float A[16];
    #pragma unroll
    for (int n = 0; n < 16; ++n) A[n] = -__expf(A_log[l*16 + n]);
    float dtw = dt_w[l], dtb = dt_b[l], Dv = Dp[l];

    // in_proj (xc pre-conv + silu(z)); sequence token t = channel block t*8..t*8+7
    float pre[8], sz[8];
    #pragma unroll
    for (int t = 0; t < 8; ++t) {
        float a0 = 0.f, a1 = 0.f;
        #pragma unroll
        for (int c = 0; c < 8; ++c) {
            float xv = xin[s * 65 + t * 8 + c];
            a0 += wi0[c] * xv; a1 += wi1[c] * xv;
        }
        pre[t] = a0; sz[t] = siluf_(a1);
    }
    // causal depthwise conv along t
    float xcv[8];
    #pragma unroll
    for (int t = 0; t < 8; ++t) {
        float v = cb + cw3 * pre[t];
        if (t >= 1) v += cw2 * pre[t-1];
        if (t >= 2) v += cw1 * pre[t-2];
        if (t >= 3) v += cw0 * pre[t-3];
        xcv[t] = siluf_(v);
    }
    #pragma unroll
    for (int t = 0; t < 8; ++t) xcs[s * 132 + t * 16 + l] = xcv[t];
    __syncthreads();

    // x-projections: lane l acts as state index n for B/C rows; dt row 0
    float dtv[8];
    #pragma unroll
    for (int t = 0; t < 8; ++t) {
        float bn = 0.f, cn = 0.f, d0 = 0.f;
        #pragma unroll
        for (int e = 0; e < 16; ++e) {
            float xv = xcs[s * 132 + t * 16 + e];
            bn += xp_w[(1 + l) * 16 + e] * xv;
            cn += xp_w[(17 + l) * 16 + e] * xv;
            d0 += xp_w[e] * xv;
        }
        Bs[s * 132 + t * 16 + l] = bn;
        Cs[s * 132 + t * 16 + l] = cn;
        dtv[t] = d0;
    }
    __syncthreads();
    float del[8];
    #pragma unroll
    for (int t = 0; t < 8; ++t) del[t] = softplusf_(dtv[t] * dtw + dtb);

    // selective scan, 16 states per lane, fully in registers
    float h[16];
    #pragma unroll
    for (int n = 0; n < 16; ++n) h[n] = 0.f;
    float yv[8];
    #pragma unroll
    for (int t = 0; t < 8; ++t) {
        float d = del[t], u = xcv[t];
        float du = d * u;
        float y = 0.f;
        const float4* Bp = (const float4*)(Bs + s * 132 + t * 16);
        const float4* Cp = (const float4*)(Cs + s * 132 + t * 16);
        #pragma unroll
        for (int q = 0; q < 4; ++q) {
            float4 Bq = Bp[q], Cq = Cp[q];
            float dA;
            dA = __expf(d*A[4*q+0]); h[4*q+0] = h[4*q+0]*dA + du*Bq.x; y += h[4*q+0]*Cq.x;
            dA = __expf(d*A[4*q+1]); h[4*q+1] = h[4*q+1]*dA + du*Bq.y; y += h[4*q+1]*Cq.y;
            dA = __expf(d*A[4*q+2]); h[4*q+2] = h[4*q+2]*dA + du*Bq.z; y += h[4*q+2]*Cq.z;
            dA = __expf(d*A[4*q+3]); h[4*q+3] = h[4*q+3]*dA + du*Bq.w; y += h[4*q+3]*Cq.w;
        }
        yv[t] = (y + u * Dv) * sz[t];
    }
    #pragma unroll
    for (int t = 0; t < 8; ++t) ys[s * 136 + t * 17 + l] = yv[t];
    __syncthreads();

    // out_proj: 64 outputs per sequence (8 t x 8 d), 4 per lane
    {
        int t = l >> 1;
        int db = (l & 1) * 4;
        #pragma unroll
        for (int jj = 0; jj < 4; ++jj) {
            int dd = db + jj;
            float acc = 0.f;
            #pragma unroll
            for (int e = 0; e < 16; ++e) acc += out_w[dd * 16 + e] * ys[s * 136 + t * 17 + e];
            outs[(t * 8 + dd) * 17 + s] = acc;   // channel c = t*8+dd
        }
    }
    __syncthreads();

    // coalesced NCHW store + GroupNorm partials (iteration k == group g)
    float sg[4], sg2[4];
    #pragma unroll
    for (int k = 0; k < 4; ++k) {
        int i = tid + k * 256;
        int c = i >> 4, j = i & 15;
        float v = outs[c * 17 + j];
        spe_raw[((size_t)b * NC + c) * HW_ + hw0 + j] = v;
        sg[k] = v; sg2[k] = v * v;
    }
    #pragma unroll
    for (int k = 0; k < 4; ++k) {
        #pragma unroll
        for (int o = 1; o < 64; o <<= 1) {
            sg[k]  += __shfl_xor(sg[k], o, 64);
            sg2[k] += __shfl_xor(sg2[k], o, 64);
        }
    }
    if ((tid & 63) == 0) {
        int w = tid >> 6;
        #pragma unroll
        for (int k = 0; k < 4; ++k) { wred[w*8 + k*2] = sg[k]; wred[w*8 + k*2 + 1] = sg2[k]; }
    }
    __syncthreads();
    if (tid < 8)
        part_spe[blockIdx.x * 8 + tid] = wred[tid] + wred[8+tid] + wred[16+tid] + wred[24+tid];
}

// ---------------------------------------------------------------------------
// K5b: reduce GN partials -> (mean, rstd) for 2 branches x 2 b x 4 groups
// ---------------------------------------------------------------------------
__global__ __launch_bounds__(256) void k5b_stats(
    const float* __restrict__ part_spa, const float* __restrict__ part_spe,
    float* __restrict__ stats)
{
    __shared__ float r1[256];
    __shared__ float fin[32];
    const int tid = threadIdx.x;
    const int combo = tid >> 4, sl = tid & 15;      // combo = b*8 + g*2 + st
    const int bb = combo >> 3, g = (combo >> 1) & 3, st = combo & 1;
    float acc = 0.f;
    for (int k = 0; k < 16; ++k)
        acc += part_spa[(bb * 256 + sl * 16 + k) * 8 + g * 2 + st];
    r1[tid] = acc;
    __syncthreads();
    if (tid < 16) { float a = 0.f; for (int k = 0; k < 16; ++k) a += r1[tid*16 + k]; fin[tid] = a; }
    __syncthreads();
    acc = 0.f;
    for (int k = 0; k < 64; ++k)
        acc += part_spe[(bb * 1024 + sl * 64 + k) * 8 + g * 2 + st];
    r1[tid] = acc;
    __syncthreads();
    if (tid < 16) { float a = 0.f; for (int k = 0; k < 16; ++k) a += r1[tid*16 + k]; fin[16 + tid] = a; }
    __syncthreads();
    if (tid < 16) {
        float S  = fin[(tid >> 3) * 16 + (tid & 7) * 2];
        float S2 = fin[(tid >> 3) * 16 + (tid & 7) * 2 + 1];
        const float N = 262144.f;     // 16 channels * 16384 positions
        float mu = S / N;
        float var = S2 / N - mu * mu;
        stats[tid * 2] = mu;
        stats[tid * 2 + 1] = rsqrtf(var + 1e-5f);
    }
}

// ---------------------------------------------------------------------------
// K6: GN-normalize + silu + residual for both branches, softmax fuse, store
// ---------------------------------------------------------------------------
__global__ __launch_bounds__(256) void k6_fuse(
    const float* __restrict__ x, const float* __restrict__ spa_raw,
    const float* __restrict__ spe_raw, const float* __restrict__ stats,
    const float* __restrict__ gwa, const float* __restrict__ gba,
    const float* __restrict__ gwe, const float* __restrict__ gbe,
    const float* __restrict__ fw, float* __restrict__ out)
{
    size_t i4 = (size_t)blockIdx.x * 256 + threadIdx.x;
    size_t base = i4 * 4;
    int b = (int)(base >> 20);
    int rem = (int)(base & 1048575);
    int c = rem >> 14;
    int g = c >> 4;
    int sidx = (b * 4 + g) * 2;
    float ma = stats[sidx],      ra = stats[sidx + 1];
    float me = stats[16 + sidx], re = stats[16 + sidx + 1];
    float wa = gwa[c], ba = gba[c], we = gwe[c], be = gbe[c];
    float f0 = fw[0], f1 = fw[1];
    float mx = fmaxf(f0, f1);
    float e0 = __expf(f0 - mx), e1 = __expf(f1 - mx);
    float inv = 1.f / (e0 + e1);
    float w0 = e0 * inv, w1 = e1 * inv;
    float4 xv = *(const float4*)(x + base);
    float4 av = *(const float4*)(spa_raw + base);
    float4 ev = *(const float4*)(spe_raw + base);
    float xr[4] = {xv.x, xv.y, xv.z, xv.w};
    float ar[4] = {av.x, av.y, av.z, av.w};
    float er[4] = {ev.x, ev.y, ev.z, ev.w};
    float orr[4];
    #pragma unroll
    for (int k = 0; k < 4; ++k) {
        float spa = siluf_((ar[k] - ma) * ra * wa + ba) + xr[k];
        float spe = siluf_((er[k] - me) * re * we + be) + xr[k];
        orr[k] = spa * w0 + spe * w1 + xr[k];
    }
    float4 ov = {orr[0], orr[1], orr[2], orr[3]};
    *(float4*)(out + base) = ov;
}

// ---------------------------------------------------------------------------
extern "C" void kernel_launch(void* const* d_in, const int* in_sizes, int n_in,
                              void* d_out, int out_size, void* d_ws, size_t ws_size,
                              hipStream_t stream)
{
    const float* x      = (const float*)d_in[0];
    const float* a_inw  = (const float*)d_in[1];
    const float* a_cw   = (const float*)d_in[2];
    const float* a_cb   = (const float*)d_in[3];
    const float* a_xp   = (const float*)d_in[4];
    const float* a_dtw  = (const float*)d_in[5];
    const float* a_dtb  = (const float*)d_in[6];
    const float* a_Alog = (const float*)d_in[7];
    const float* a_D    = (const float*)d_in[8];
    const float* a_ow   = (const float*)d_in[9];
    const float* e_inw  = (const float*)d_in[10];
    const float* e_cw   = (const float*)d_in[11];
    const float* e_cb   = (const float*)d_in[12];
    const float* e_xp   = (const float*)d_in[13];
    const float* e_dtw  = (const float*)d_in[14];
    const float* e_dtb  = (const float*)d_in[15];
    const float* e_Alog = (const float*)d_in[16];
    const float* e_D    = (const float*)d_in[17];
    const float* e_ow   = (const float*)d_in[18];
    const float* gwa    = (const float*)d_in[19];
    const float* gba    = (const float*)d_in[20];
    const float* gwe    = (const float*)d_in[21];
    const float* gbe    = (const float*)d_in[22];
    const float* fw     = (const float*)d_in[23];

    float* ws    = (float*)d_ws;
    float* xc    = ws;                    // 32768*128
    float* sz    = xc    + 4194304;       // 32768*128
    float* delta = sz    + 4194304;       // 32768*128
    float* Bm    = delta + 4194304;       // 32768*16
    float* Cm    = Bm    + 524288;        // 32768*16
    float* cumA  = Cm    + 524288;        // 2*256*2048
    float* hsum  = cumA  + 1048576;
    float* Hin   = hsum  + 1048576;
    float* spa_r = Hin   + 1048576;       // 2*64*16384
    float* spe_r = spa_r + 2097152;
    float* pspa  = spe_r + 2097152;       // 512*8
    float* pspe  = pspa  + 4096;          // 2048*8
    float* stats = pspe  + 16384;         // 32

    k1_spatial_pre<<<512, 256, 0, stream>>>(x, a_inw, a_cw, a_cb, a_xp, a_dtw, a_dtb,
                                            xc, sz, delta, Bm, Cm);
    k2_scan1<<<512, 256, 0, stream>>>(delta, xc, Bm, a_Alog, cumA, hsum);
    k3_combine<<<16, 256, 0, stream>>>(cumA, hsum, Hin);
    k5_spectral<<<2048, 256, 0, stream>>>(x, e_inw, e_cw, e_cb, e_xp, e_dtw, e_dtb,
                                          e_Alog, e_D, e_ow, spe_r, pspe);
    k4_scan2<<<512, 256, 0, stream>>>(delta, xc, sz, Bm, Cm, a_Alog, a_D, Hin, a_ow,
                                      spa_r, pspa);
    k5b_stats<<<1, 256, 0, stream>>>(pspa, pspe, stats);
    k6_fuse<<<2048, 256, 0, stream>>>(x, spa_r, spe_r, stats, gwa, gba, gwe, gbe, fw,
                                      (float*)d_out);
}

// Round 2
// 558.333 us; speedup vs baseline: 1.0927x; 1.0927x over previous
//
#include <hip/hip_runtime.h>
#include <math.h>

// ---------------------------------------------------------------------------
// Problem constants
//   x: (B=2, C=64, H=128, W=128) fp32, HW = 16384 tokens per batch
//   spatial mamba: d_model=64, d_inner=128, dt_rank=4, d_state=16, L=16384
//   spectral mamba: per-pixel sequence of TOKEN=8 over channel groups of 8,
//                   d_model=8, d_inner=16, dt_rank=1, d_state=16
// ---------------------------------------------------------------------------

#define NB 2
#define NC 64
#define HW_ 16384
#define SCH 256          // spatial scan chunks per batch
#define SLC 64           // tokens per chunk (16384/256)

__device__ __forceinline__ float sigmoidf_(float v) { return 1.f / (1.f + __expf(-v)); }
__device__ __forceinline__ float siluf_(float v)    { return v * sigmoidf_(v); }
__device__ __forceinline__ float softplusf_(float v) {
    return v > 0.f ? v + log1pf(__expf(-v)) : log1pf(__expf(v));
}

// ---------------------------------------------------------------------------
// K1: spatial in_proj + depthwise causal conv + silu + x-proj(B,C,dt) + delta
// grid 512 (= 2 b * 256 tiles of 64 tokens), block 256
// LDS: pre-activations region reused for post-conv tile (phased, barriered)
// ---------------------------------------------------------------------------
#define K1_XS_OFF 8576       // floats; pre/xcl region is [0, 8576)
#define K1_XS_STR 68         // x tile row stride (4-aligned, bank-rotating)
#define K1_XCL_STR 132       // conv-output tile row stride

__global__ __launch_bounds__(256) void k1_spatial_pre(
    const float* __restrict__ x, const float* __restrict__ in_w,
    const float* __restrict__ conv_w, const float* __restrict__ conv_b,
    const float* __restrict__ xp_w, const float* __restrict__ dt_w,
    const float* __restrict__ dt_b,
    float* __restrict__ xc_g, float* __restrict__ sz_g,
    float* __restrict__ delta_g, float* __restrict__ Bm_g, float* __restrict__ Cm_g)
{
    __shared__ float smem[13132];   // 8576 (pre/xcl) + 67*68 (x tile)
    __shared__ float dtl[256];      // dt-projection per (token, r)
    const int tid = threadIdx.x;
    const int b   = blockIdx.x >> 8;
    const int l0  = (blockIdx.x & 255) << 6;

    // ---- Phase A: load x tile, tokens l0-3 .. l0+63, layout [tok][c] ----
    for (int i = tid; i < 67 * 64; i += 256) {
        int c = i / 67;
        int tok = i - c * 67;
        int l = l0 + tok - 3;
        float v = (l >= 0) ? x[((size_t)b * NC + c) * HW_ + l] : 0.f;
        smem[K1_XS_OFF + tok * K1_XS_STR + c] = v;
    }
    __syncthreads();

    // ---- Phase B: in_proj (256x64 matvec per token), weights in VGPRs ----
    {
        const int e = tid & 127;
        const int half = tid >> 7;
        float w[64];
        #pragma unroll
        for (int q = 0; q < 16; ++q) {
            float4 wv = *(const float4*)(in_w + e * 64 + q * 4);
            w[q*4] = wv.x; w[q*4+1] = wv.y; w[q*4+2] = wv.z; w[q*4+3] = wv.w;
        }
        int t0 = half ? 34 : 0, t1 = half ? 67 : 34;
        for (int tok = t0; tok < t1; ++tok) {
            const float4* xr = (const float4*)(smem + K1_XS_OFF + tok * K1_XS_STR);
            float acc = 0.f;
            #pragma unroll
            for (int q = 0; q < 16; ++q) {
                float4 xv = xr[q];
                acc += w[q*4]*xv.x + w[q*4+1]*xv.y + w[q*4+2]*xv.z + w[q*4+3]*xv.w;
            }
            smem[tok * 128 + e] = acc;      // pre-conv activation
        }
        #pragma unroll
        for (int q = 0; q < 16; ++q) {
            float4 wv = *(const float4*)(in_w + (128 + e) * 64 + q * 4);
            w[q*4] = wv.x; w[q*4+1] = wv.y; w[q*4+2] = wv.z; w[q*4+3] = wv.w;
        }
        int z0 = half * 32;
        for (int tok = z0; tok < z0 + 32; ++tok) {
            const float4* xr = (const float4*)(smem + K1_XS_OFF + (tok + 3) * K1_XS_STR);
            float acc = 0.f;
            #pragma unroll
            for (int q = 0; q < 16; ++q) {
                float4 xv = xr[q];
                acc += w[q*4]*xv.x + w[q*4+1]*xv.y + w[q*4+2]*xv.z + w[q*4+3]*xv.w;
            }
            sz_g[((size_t)(b * HW_ + l0 + tok)) * 128 + e] = siluf_(acc);  // silu(z)
        }
    }
    __syncthreads();

    // ---- Phase C: depthwise causal conv (k=4) + bias + silu ----
    {
        const int e = tid & 127;
        float cw0 = conv_w[e*4], cw1 = conv_w[e*4+1], cw2 = conv_w[e*4+2], cw3 = conv_w[e*4+3];
        float cb = conv_b[e];
        float r[32];
        #pragma unroll
        for (int k = 0; k < 32; ++k) {
            int tok = (tid + k * 256) >> 7;
            float v = cb + cw0 * smem[(tok+0)*128 + e] + cw1 * smem[(tok+1)*128 + e]
                         + cw2 * smem[(tok+2)*128 + e] + cw3 * smem[(tok+3)*128 + e];
            v = siluf_(v);
            r[k] = v;
            xc_g[((size_t)(b * HW_ + l0 + tok)) * 128 + e] = v;
        }
        __syncthreads();
        #pragma unroll
        for (int k = 0; k < 32; ++k) {
            int tok = (tid + k * 256) >> 7;
            smem[tok * K1_XCL_STR + e] = r[k];   // overwrite pre region (barriered)
        }
    }
    __syncthreads();

    // ---- Phase D1: B (rows 4..19) and C (rows 20..35) projections ----
    for (int i = tid; i < 64 * 32; i += 256) {
        int tok = i >> 5;
        int f = i & 31;
        const float4* xr = (const float4*)(smem + tok * K1_XCL_STR);
        const float4* wr = (const float4*)(xp_w + (4 + f) * 128);
        float acc = 0.f;
        #pragma unroll
        for (int q = 0; q < 32; ++q) {
            float4 a = xr[q], w4 = wr[q];
            acc += a.x*w4.x + a.y*w4.y + a.z*w4.z + a.w*w4.w;
        }
        size_t row = (size_t)(b * HW_ + l0 + tok);
        if (f < 16) Bm_g[row * 16 + f] = acc;
        else        Cm_g[row * 16 + (f - 16)] = acc;
    }
    // ---- Phase D2: dt projection (rows 0..3), one (token,r) per thread ----
    {
        int tok = tid >> 2;
        int rr = tid & 3;
        const float4* xr = (const float4*)(smem + tok * K1_XCL_STR);
        const float4* wr = (const float4*)(xp_w + rr * 128);
        float acc = 0.f;
        #pragma unroll
        for (int q = 0; q < 32; ++q) {
            float4 a = xr[q], w4 = wr[q];
            acc += a.x*w4.x + a.y*w4.y + a.z*w4.z + a.w*w4.w;
        }
        dtl[tid] = acc;
    }
    __syncthreads();
    // ---- Phase D3: delta = softplus(dt @ dt_w^T + dt_b) ----
    {
        const int e = tid & 127;
        float w0 = dt_w[e*4], w1 = dt_w[e*4+1], w2 = dt_w[e*4+2], w3 = dt_w[e*4+3];
        float bb = dt_b[e];
        #pragma unroll
        for (int k = 0; k < 32; ++k) {
            int tok = (tid + k * 256) >> 7;
            float4 dv = *(const float4*)(dtl + tok * 4);
            float v = bb + w0*dv.x + w1*dv.y + w2*dv.z + w3*dv.w;
            delta_g[((size_t)(b * HW_ + l0 + tok)) * 128 + e] = softplusf_(v);
        }
    }
}

// ---------------------------------------------------------------------------
// K2: spatial scan pass 1 — per-chunk summaries (cumulative dA product, local h)
// grid 512 (b*256 chunks), block 256: thread = (e, n-half), 8 states each
// ---------------------------------------------------------------------------
__global__ __launch_bounds__(256) void k2_scan1(
    const float* __restrict__ delta_g, const float* __restrict__ xc_g,
    const float* __restrict__ Bm_g, const float* __restrict__ A_log,
    float* __restrict__ cumA_g, float* __restrict__ hsum_g)
{
    const int tid = threadIdx.x;
    const int b = blockIdx.x >> 8;
    const int ch = blockIdx.x & 255;
    const int e = tid >> 1;
    const int n0 = (tid & 1) * 8;
    float A[8];
    #pragma unroll
    for (int j = 0; j < 8; ++j) A[j] = -__expf(A_log[e * 16 + n0 + j]);
    float h[8], cA[8];
    #pragma unroll
    for (int j = 0; j < 8; ++j) { h[j] = 0.f; cA[j] = 1.f; }
    const size_t rowbase = (size_t)b * HW_ + ch * SLC;
    for (int t = 0; t < SLC; ++t) {
        size_t row = rowbase + t;
        float d = delta_g[row * 128 + e];
        float u = xc_g[row * 128 + e];
        float4 b0 = *(const float4*)(Bm_g + row * 16 + n0);
        float4 b1 = *(const float4*)(Bm_g + row * 16 + n0 + 4);
        float Bv[8]; *(float4*)(Bv) = b0; *(float4*)(Bv + 4) = b1;
        float du = d * u;
        #pragma unroll
        for (int j = 0; j < 8; ++j) {
            float dA = __expf(d * A[j]);
            h[j] = h[j] * dA + du * Bv[j];
            cA[j] *= dA;
        }
    }
    size_t so = ((size_t)(b * SCH + ch)) * 2048 + tid * 8;
    #pragma unroll
    for (int j = 0; j < 8; ++j) { cumA_g[so + j] = cA[j]; hsum_g[so + j] = h[j]; }
}

// ---------------------------------------------------------------------------
// K3: cross-chunk exclusive combine (4096 independent streams, 256 steps)
// ---------------------------------------------------------------------------
__global__ __launch_bounds__(256) void k3_combine(
    const float* __restrict__ cumA_g, const float* __restrict__ hsum_g,
    float* __restrict__ Hin_g)
{
    int gid = blockIdx.x * 256 + threadIdx.x;     // 0..4095
    int b = gid >> 11;
    int en = gid & 2047;
    float st = 0.f;
    size_t o = (size_t)b * SCH * 2048 + en;
    #pragma unroll 4
    for (int ch = 0; ch < SCH; ++ch) {
        Hin_g[o] = st;
        st = st * cumA_g[o] + hsum_g[o];
        o += 2048;
    }
}

// ---------------------------------------------------------------------------
// K4: spatial scan pass 2 + y gating + out_proj + NCHW store + GN partials
// grid 512, block 256
// ---------------------------------------------------------------------------
__global__ __launch_bounds__(256) void k4_scan2(
    const float* __restrict__ delta_g, const float* __restrict__ xc_g,
    const float* __restrict__ sz_g, const float* __restrict__ Bm_g,
    const float* __restrict__ Cm_g, const float* __restrict__ A_log,
    const float* __restrict__ Dp, const float* __restrict__ Hin_g,
    const float* __restrict__ out_w,
    float* __restrict__ spa_raw, float* __restrict__ part_spa)
{
    __shared__ float ytile[SLC * 128];   // y'(t,e)
    __shared__ float otile[64 * 65];     // out(c,t), padded
    __shared__ float wred[32];
    const int tid = threadIdx.x;
    const int b = blockIdx.x >> 8;
    const int ch = blockIdx.x & 255;
    const int e = tid >> 1;
    const int nh = tid & 1;
    const int n0 = nh * 8;
    float A[8];
    #pragma unroll
    for (int j = 0; j < 8; ++j) A[j] = -__expf(A_log[e * 16 + n0 + j]);
    float Dv = Dp[e];
    float h[8];
    size_t so = ((size_t)(b * SCH + ch)) * 2048 + tid * 8;
    #pragma unroll
    for (int j = 0; j < 8; ++j) h[j] = Hin_g[so + j];
    const size_t rowbase = (size_t)b * HW_ + ch * SLC;
    for (int t = 0; t < SLC; ++t) {
        size_t row = rowbase + t;
        float d = delta_g[row * 128 + e];
        float u = xc_g[row * 128 + e];
        float4 b0 = *(const float4*)(Bm_g + row * 16 + n0);
        float4 b1 = *(const float4*)(Bm_g + row * 16 + n0 + 4);
        float4 c0 = *(const float4*)(Cm_g + row * 16 + n0);
        float4 c1 = *(const float4*)(Cm_g + row * 16 + n0 + 4);
        float Bv[8]; *(float4*)(Bv) = b0; *(float4*)(Bv + 4) = b1;
        float Cv[8]; *(float4*)(Cv) = c0; *(float4*)(Cv + 4) = c1;
        float du = d * u;
        float y = 0.f;
        #pragma unroll
        for (int j = 0; j < 8; ++j) {
            float dA = __expf(d * A[j]);
            h[j] = h[j] * dA + du * Bv[j];
            y += h[j] * Cv[j];
        }
        y += __shfl_xor(y, 1, 64);          // combine both n-halves
        if (nh == 0) {
            float szv = sz_g[row * 128 + e];
            ytile[t * 128 + e] = (y + u * Dv) * szv;
        }
    }
    __syncthreads();
    // out_proj: out(c,t) = sum_e out_w[c][e] * y'(t,e)
    for (int i = tid; i < 64 * SLC; i += 256) {
        int c = i & 63, t = i >> 6;
        const float4* wr = (const float4*)(out_w + c * 128);
        const float4* yr = (const float4*)(ytile + t * 128);
        float acc = 0.f;
        #pragma unroll
        for (int q = 0; q < 32; ++q) {
            float4 w4 = wr[q], yv4 = yr[q];
            acc += w4.x*yv4.x + w4.y*yv4.y + w4.z*yv4.z + w4.w*yv4.w;
        }
        otile[c * 65 + t] = acc;
    }
    __syncthreads();
    for (int i = tid; i < 64 * SLC; i += 256) {
        int c = i >> 6, t = i & 63;
        spa_raw[((size_t)b * NC + c) * HW_ + ch * SLC + t] = otile[c * 65 + t];
    }
    // GroupNorm partial sums (4 groups of 16 channels)
    float s[4], s2[4];
    #pragma unroll
    for (int g = 0; g < 4; ++g) {
        float a = 0.f, a2 = 0.f;
        for (int i = tid; i < 1024; i += 256) {
            int c = 16 * g + (i >> 6), t = i & 63;
            float v = otile[c * 65 + t];
            a += v; a2 += v * v;
        }
        s[g] = a; s2[g] = a2;
    }
    #pragma unroll
    for (int g = 0; g < 4; ++g) {
        #pragma unroll
        for (int o = 1; o < 64; o <<= 1) {
            s[g]  += __shfl_xor(s[g], o, 64);
            s2[g] += __shfl_xor(s2[g], o, 64);
        }
    }
    if ((tid & 63) == 0) {
        int w = tid >> 6;
        #pragma unroll
        for (int g = 0; g < 4; ++g) { wred[w*8 + g*2] = s[g]; wred[w*8 + g*2 + 1] = s2[g]; }
    }
    __syncthreads();
    if (tid < 8)
        part_spa[blockIdx.x * 8 + tid] = wred[tid] + wred[8+tid] + wred[16+tid] + wred[24+tid];
}

// ---------------------------------------------------------------------------
// K5 v2: whole spectral mamba fused, shuffle-based (no LDS for projections).
// 16 lanes per pixel-sequence, 16 seq/block. grid 2048, block 256.
// All weights hoisted to registers; cross-lane via ds_bpermute (__shfl).
// LDS only: x staging (4.2 KB) + y tile (8.7 KB) + out tile (4.4 KB).
// ---------------------------------------------------------------------------
__global__ __launch_bounds__(256, 4) void k5_spectral(
    const float* __restrict__ x, const float* __restrict__ in_w,
    const float* __restrict__ conv_w, const float* __restrict__ conv_b,
    const float* __restrict__ xp_w, const float* __restrict__ dt_w,
    const float* __restrict__ dt_b, const float* __restrict__ A_log,
    const float* __restrict__ Dp, const float* __restrict__ out_w,
    float* __restrict__ spe_raw, float* __restrict__ part_spe)
{
    __shared__ float xin[16 * 65];    // [seq][c]
    __shared__ float ys[16 * 136];    // [seq][t*17+e]
    __shared__ float outs[64 * 17];   // [c][seq]
    __shared__ float wred[32];
    const int tid = threadIdx.x;
    const int b = blockIdx.x >> 10;
    const int hw0 = (blockIdx.x & 1023) << 4;
    const int s = tid >> 4;       // sequence in block (0..15)
    const int l = tid & 15;       // inner-channel e / state n role (0..15)
    const int base = tid & 48;    // 16-lane group base within wave

    for (int i = tid; i < 1024; i += 256) {
        int c = i >> 4, j = i & 15;
        xin[j * 65 + c] = x[((size_t)b * NC + c) * HW_ + hw0 + j];
    }

    // ---- hoist all weights into registers (uniform rows -> SGPRs) ----
    float wdt[16];
    #pragma unroll
    for (int e = 0; e < 16; ++e) wdt[e] = xp_w[e];           // dt row (uniform)
    float wi0[8], wi1[8];
    #pragma unroll
    for (int c = 0; c < 8; ++c) { wi0[c] = in_w[l*8 + c]; wi1[c] = in_w[(l+16)*8 + c]; }
    float cw0 = conv_w[l*4], cw1 = conv_w[l*4+1], cw2 = conv_w[l*4+2], cw3 = conv_w[l*4+3];
    float cb = conv_b[l];
    float dtw = dt_w[l], dtb = dt_b[l];
    __syncthreads();

    // ---- in_proj: pre-conv xc + silu(z), all in registers ----
    float pre[8], sz[8];
    #pragma unroll
    for (int t = 0; t < 8; ++t) {
        float a0 = 0.f, a1 = 0.f;
        #pragma unroll
        for (int c = 0; c < 8; ++c) {
            float xv = xin[s * 65 + t * 8 + c];
            a0 += wi0[c] * xv; a1 += wi1[c] * xv;
        }
        pre[t] = a0; sz[t] = siluf_(a1);
    }
    // ---- causal depthwise conv along t (registers) ----
    float xcv[8];
    #pragma unroll
    for (int t = 0; t < 8; ++t) {
        float v = cb + cw3 * pre[t];
        if (t >= 1) v += cw2 * pre[t-1];
        if (t >= 2) v += cw1 * pre[t-2];
        if (t >= 3) v += cw0 * pre[t-3];
        xcv[t] = siluf_(v);
    }

    // ---- x-projections via shuffle broadcast of xcv across the 16-lane group.
    //      lane l computes B_n=l, C_n=l rows; dt row is lane-redundant. ----
    float wB[16], wC[16];
    #pragma unroll
    for (int e = 0; e < 16; ++e) {
        wB[e] = xp_w[(1 + l) * 16 + e];
        wC[e] = xp_w[(17 + l) * 16 + e];
    }
    float bn[8], cn[8], del[8];
    #pragma unroll
    for (int t = 0; t < 8; ++t) {
        float b_ = 0.f, c_ = 0.f, d0 = 0.f;
        #pragma unroll
        for (int e = 0; e < 16; ++e) {
            float xv = __shfl(xcv[t], base + e, 64);
            b_ += wB[e] * xv; c_ += wC[e] * xv; d0 += wdt[e] * xv;
        }
        bn[t] = b_; cn[t] = c_;
        del[t] = softplusf_(d0 * dtw + dtb);
    }

    // ---- selective scan, 16 states per lane, B/C gathered via shuffle ----
    float A[16];
    #pragma unroll
    for (int n = 0; n < 16; ++n) A[n] = -__expf(A_log[l * 16 + n]);
    float Dv = Dp[l];
    float h[16];
    #pragma unroll
    for (int n = 0; n < 16; ++n) h[n] = 0.f;
    #pragma unroll
    for (int t = 0; t < 8; ++t) {
        float d = del[t], u = xcv[t];
        float du = d * u;
        float y = 0.f;
        #pragma unroll
        for (int n = 0; n < 16; ++n) {
            float Bn = __shfl(bn[t], base + n, 64);
            float Cn = __shfl(cn[t], base + n, 64);
            float dA = __expf(d * A[n]);
            h[n] = h[n] * dA + du * Bn;
            y += h[n] * Cn;
        }
        ys[s * 136 + t * 17 + l] = (y + u * Dv) * sz[t];
    }
    __syncthreads();

    // ---- out_proj: 64 outputs per sequence (8 t x 8 d), 4 per lane ----
    {
        int t = l >> 1;
        int db = (l & 1) * 4;
        #pragma unroll
        for (int jj = 0; jj < 4; ++jj) {
            int dd = db + jj;
            float acc = 0.f;
            #pragma unroll
            for (int e = 0; e < 16; ++e) acc += out_w[dd * 16 + e] * ys[s * 136 + t * 17 + e];
            outs[(t * 8 + dd) * 17 + s] = acc;   // channel c = t*8+dd
        }
    }
    __syncthreads();

    // ---- coalesced NCHW store + GroupNorm partials (iteration k == group g) ----
    float sg[4], sg2[4];
    #pragma unroll
    for (int k = 0; k < 4; ++k) {
        int i = tid + k * 256;
        int c = i >> 4, j = i & 15;
        float v = outs[c * 17 + j];
        spe_raw[((size_t)b * NC + c) * HW_ + hw0 + j] = v;
        sg[k] = v; sg2[k] = v * v;
    }
    #pragma unroll
    for (int k = 0; k < 4; ++k) {
        #pragma unroll
        for (int o = 1; o < 64; o <<= 1) {
            sg[k]  += __shfl_xor(sg[k], o, 64);
            sg2[k] += __shfl_xor(sg2[k], o, 64);
        }
    }
    if ((tid & 63) == 0) {
        int w = tid >> 6;
        #pragma unroll
        for (int k = 0; k < 4; ++k) { wred[w*8 + k*2] = sg[k]; wred[w*8 + k*2 + 1] = sg2[k]; }
    }
    __syncthreads();
    if (tid < 8)
        part_spe[blockIdx.x * 8 + tid] = wred[tid] + wred[8+tid] + wred[16+tid] + wred[24+tid];
}

// ---------------------------------------------------------------------------
// K5b: reduce GN partials -> (mean, rstd) for 2 branches x 2 b x 4 groups
// ---------------------------------------------------------------------------
__global__ __launch_bounds__(256) void k5b_stats(
    const float* __restrict__ part_spa, const float* __restrict__ part_spe,
    float* __restrict__ stats)
{
    __shared__ float r1[256];
    __shared__ float fin[32];
    const int tid = threadIdx.x;
    const int combo = tid >> 4, sl = tid & 15;      // combo = b*8 + g*2 + st
    const int bb = combo >> 3, g = (combo >> 1) & 3, st = combo & 1;
    float acc = 0.f;
    for (int k = 0; k < 16; ++k)
        acc += part_spa[(bb * 256 + sl * 16 + k) * 8 + g * 2 + st];
    r1[tid] = acc;
    __syncthreads();
    if (tid < 16) { float a = 0.f; for (int k = 0; k < 16; ++k) a += r1[tid*16 + k]; fin[tid] = a; }
    __syncthreads();
    acc = 0.f;
    for (int k = 0; k < 64; ++k)
        acc += part_spe[(bb * 1024 + sl * 64 + k) * 8 + g * 2 + st];
    r1[tid] = acc;
    __syncthreads();
    if (tid < 16) { float a = 0.f; for (int k = 0; k < 16; ++k) a += r1[tid*16 + k]; fin[16 + tid] = a; }
    __syncthreads();
    if (tid < 16) {
        float S  = fin[(tid >> 3) * 16 + (tid & 7) * 2];
        float S2 = fin[(tid >> 3) * 16 + (tid & 7) * 2 + 1];
        const float N = 262144.f;     // 16 channels * 16384 positions
        float mu = S / N;
        float var = S2 / N - mu * mu;
        stats[tid * 2] = mu;
        stats[tid * 2 + 1] = rsqrtf(var + 1e-5f);
    }
}

// ---------------------------------------------------------------------------
// K6: GN-normalize + silu + residual for both branches, softmax fuse, store
// ---------------------------------------------------------------------------
__global__ __launch_bounds__(256) void k6_fuse(
    const float* __restrict__ x, const float* __restrict__ spa_raw,
    const float* __restrict__ spe_raw, const float* __restrict__ stats,
    const float* __restrict__ gwa, const float* __restrict__ gba,
    const float* __restrict__ gwe, const float* __restrict__ gbe,
    const float* __restrict__ fw, float* __restrict__ out)
{
    size_t i4 = (size_t)blockIdx.x * 256 + threadIdx.x;
    size_t base = i4 * 4;
    int b = (int)(base >> 20);
    int rem = (int)(base & 1048575);
    int c = rem >> 14;
    int g = c >> 4;
    int sidx = (b * 4 + g) * 2;
    float ma = stats[sidx],      ra = stats[sidx + 1];
    float me = stats[16 + sidx], re = stats[16 + sidx + 1];
    float wa = gwa[c], ba = gba[c], we = gwe[c], be = gbe[c];
    float f0 = fw[0], f1 = fw[1];
    float mx = fmaxf(f0, f1);
    float e0 = __expf(f0 - mx), e1 = __expf(f1 - mx);
    float inv = 1.f / (e0 + e1);
    float w0 = e0 * inv, w1 = e1 * inv;
    float4 xv = *(const float4*)(x + base);
    float4 av = *(const float4*)(spa_raw + base);
    float4 ev = *(const float4*)(spe_raw + base);
    float xr[4] = {xv.x, xv.y, xv.z, xv.w};
    float ar[4] = {av.x, av.y, av.z, av.w};
    float er[4] = {ev.x, ev.y, ev.z, ev.w};
    float orr[4];
    #pragma unroll
    for (int k = 0; k < 4; ++k) {
        float spa = siluf_((ar[k] - ma) * ra * wa + ba) + xr[k];
        float spe = siluf_((er[k] - me) * re * we + be) + xr[k];
        orr[k] = spa * w0 + spe * w1 + xr[k];
    }
    float4 ov = {orr[0], orr[1], orr[2], orr[3]};
    *(float4*)(out + base) = ov;
}

// ---------------------------------------------------------------------------
extern "C" void kernel_launch(void* const* d_in, const int* in_sizes, int n_in,
                              void* d_out, int out_size, void* d_ws, size_t ws_size,
                              hipStream_t stream)
{
    const float* x      = (const float*)d_in[0];
    const float* a_inw  = (const float*)d_in[1];
    const float* a_cw   = (const float*)d_in[2];
    const float* a_cb   = (const float*)d_in[3];
    const float* a_xp   = (const float*)d_in[4];
    const float* a_dtw  = (const float*)d_in[5];
    const float* a_dtb  = (const float*)d_in[6];
    const float* a_Alog = (const float*)d_in[7];
    const float* a_D    = (const float*)d_in[8];
    const float* a_ow   = (const float*)d_in[9];
    const float* e_inw  = (const float*)d_in[10];
    const float* e_cw   = (const float*)d_in[11];
    const float* e_cb   = (const float*)d_in[12];
    const float* e_xp   = (const float*)d_in[13];
    const float* e_dtw  = (const float*)d_in[14];
    const float* e_dtb  = (const float*)d_in[15];
    const float* e_Alog = (const float*)d_in[16];
    const float* e_D    = (const float*)d_in[17];
    const float* e_ow   = (const float*)d_in[18];
    const float* gwa    = (const float*)d_in[19];
    const float* gba    = (const float*)d_in[20];
    const float* gwe    = (const float*)d_in[21];
    const float* gbe    = (const float*)d_in[22];
    const float* fw     = (const float*)d_in[23];

    float* ws    = (float*)d_ws;
    float* xc    = ws;                    // 32768*128
    float* sz    = xc    + 4194304;       // 32768*128
    float* delta = sz    + 4194304;       // 32768*128
    float* Bm    = delta + 4194304;       // 32768*16
    float* Cm    = Bm    + 524288;        // 32768*16
    float* cumA  = Cm    + 524288;        // 2*256*2048
    float* hsum  = cumA  + 1048576;
    float* Hin   = hsum  + 1048576;
    float* spa_r = Hin   + 1048576;       // 2*64*16384
    float* spe_r = spa_r + 2097152;
    float* pspa  = spe_r + 2097152;       // 512*8
    float* pspe  = pspa  + 4096;          // 2048*8
    float* stats = pspe  + 16384;         // 32

    k1_spatial_pre<<<512, 256, 0, stream>>>(x, a_inw, a_cw, a_cb, a_xp, a_dtw, a_dtb,
                                            xc, sz, delta, Bm, Cm);
    k2_scan1<<<512, 256, 0, stream>>>(delta, xc, Bm, a_Alog, cumA, hsum);
    k3_combine<<<16, 256, 0, stream>>>(cumA, hsum, Hin);
    k5_spectral<<<2048, 256, 0, stream>>>(x, e_inw, e_cw, e_cb, e_xp, e_dtw, e_dtb,
                                          e_Alog, e_D, e_ow, spe_r, pspe);
    k4_scan2<<<512, 256, 0, stream>>>(delta, xc, sz, Bm, Cm, a_Alog, a_D, Hin, a_ow,
                                      spa_r, pspa);
    k5b_stats<<<1, 256, 0, stream>>>(pspa, pspe, stats);
    k6_fuse<<<2048, 256, 0, stream>>>(x, spa_r, spe_r, stats, gwa, gba, gwe, gbe, fw,
                                      (float*)d_out);
}

// Round 3
// 438.213 us; speedup vs baseline: 1.3923x; 1.2741x over previous
//
#include <hip/hip_runtime.h>
#include <math.h>

// ---------------------------------------------------------------------------
// Problem constants
//   x: (B=2, C=64, H=128, W=128) fp32, HW = 16384 tokens per batch
//   spatial mamba: d_model=64, d_inner=128, dt_rank=4, d_state=16, L=16384
//   spectral mamba: per-pixel sequence of TOKEN=8 over channel groups of 8,
//                   d_model=8, d_inner=16, dt_rank=1, d_state=16
// ---------------------------------------------------------------------------

#define NB 2
#define NC 64
#define HW_ 16384
#define SCH 256          // spatial scan chunks per batch
#define SLC 64           // tokens per chunk (16384/256)

__device__ __forceinline__ float sigmoidf_(float v) { return 1.f / (1.f + __expf(-v)); }
__device__ __forceinline__ float siluf_(float v)    { return v * sigmoidf_(v); }
__device__ __forceinline__ float softplusf_(float v) {
    return v > 0.f ? v + log1pf(__expf(-v)) : log1pf(__expf(v));
}

// ---------------------------------------------------------------------------
// K1: spatial in_proj + depthwise causal conv + silu + x-proj(B,C,dt) + delta
// grid 512 (= 2 b * 256 tiles of 64 tokens), block 256
// LDS: pre-activations region reused for post-conv tile (phased, barriered)
// ---------------------------------------------------------------------------
#define K1_XS_OFF 8576       // floats; pre/xcl region is [0, 8576)
#define K1_XS_STR 68         // x tile row stride (4-aligned, bank-rotating)
#define K1_XCL_STR 132       // conv-output tile row stride

__global__ __launch_bounds__(256) void k1_spatial_pre(
    const float* __restrict__ x, const float* __restrict__ in_w,
    const float* __restrict__ conv_w, const float* __restrict__ conv_b,
    const float* __restrict__ xp_w, const float* __restrict__ dt_w,
    const float* __restrict__ dt_b,
    float* __restrict__ xc_g, float* __restrict__ sz_g,
    float* __restrict__ delta_g, float* __restrict__ Bm_g, float* __restrict__ Cm_g)
{
    __shared__ float smem[13132];   // 8576 (pre/xcl) + 67*68 (x tile)
    __shared__ float dtl[256];      // dt-projection per (token, r)
    const int tid = threadIdx.x;
    const int b   = blockIdx.x >> 8;
    const int l0  = (blockIdx.x & 255) << 6;

    // ---- Phase A: load x tile, tokens l0-3 .. l0+63, layout [tok][c] ----
    for (int i = tid; i < 67 * 64; i += 256) {
        int c = i / 67;
        int tok = i - c * 67;
        int l = l0 + tok - 3;
        float v = (l >= 0) ? x[((size_t)b * NC + c) * HW_ + l] : 0.f;
        smem[K1_XS_OFF + tok * K1_XS_STR + c] = v;
    }
    __syncthreads();

    // ---- Phase B: in_proj (256x64 matvec per token), weights in VGPRs ----
    {
        const int e = tid & 127;
        const int half = tid >> 7;
        float w[64];
        #pragma unroll
        for (int q = 0; q < 16; ++q) {
            float4 wv = *(const float4*)(in_w + e * 64 + q * 4);
            w[q*4] = wv.x; w[q*4+1] = wv.y; w[q*4+2] = wv.z; w[q*4+3] = wv.w;
        }
        int t0 = half ? 34 : 0, t1 = half ? 67 : 34;
        for (int tok = t0; tok < t1; ++tok) {
            const float4* xr = (const float4*)(smem + K1_XS_OFF + tok * K1_XS_STR);
            float acc = 0.f;
            #pragma unroll
            for (int q = 0; q < 16; ++q) {
                float4 xv = xr[q];
                acc += w[q*4]*xv.x + w[q*4+1]*xv.y + w[q*4+2]*xv.z + w[q*4+3]*xv.w;
            }
            smem[tok * 128 + e] = acc;      // pre-conv activation
        }
        #pragma unroll
        for (int q = 0; q < 16; ++q) {
            float4 wv = *(const float4*)(in_w + (128 + e) * 64 + q * 4);
            w[q*4] = wv.x; w[q*4+1] = wv.y; w[q*4+2] = wv.z; w[q*4+3] = wv.w;
        }
        int z0 = half * 32;
        for (int tok = z0; tok < z0 + 32; ++tok) {
            const float4* xr = (const float4*)(smem + K1_XS_OFF + (tok + 3) * K1_XS_STR);
            float acc = 0.f;
            #pragma unroll
            for (int q = 0; q < 16; ++q) {
                float4 xv = xr[q];
                acc += w[q*4]*xv.x + w[q*4+1]*xv.y + w[q*4+2]*xv.z + w[q*4+3]*xv.w;
            }
            sz_g[((size_t)(b * HW_ + l0 + tok)) * 128 + e] = siluf_(acc);  // silu(z)
        }
    }
    __syncthreads();

    // ---- Phase C: depthwise causal conv (k=4) + bias + silu ----
    {
        const int e = tid & 127;
        float cw0 = conv_w[e*4], cw1 = conv_w[e*4+1], cw2 = conv_w[e*4+2], cw3 = conv_w[e*4+3];
        float cb = conv_b[e];
        float r[32];
        #pragma unroll
        for (int k = 0; k < 32; ++k) {
            int tok = (tid + k * 256) >> 7;
            float v = cb + cw0 * smem[(tok+0)*128 + e] + cw1 * smem[(tok+1)*128 + e]
                         + cw2 * smem[(tok+2)*128 + e] + cw3 * smem[(tok+3)*128 + e];
            v = siluf_(v);
            r[k] = v;
            xc_g[((size_t)(b * HW_ + l0 + tok)) * 128 + e] = v;
        }
        __syncthreads();
        #pragma unroll
        for (int k = 0; k < 32; ++k) {
            int tok = (tid + k * 256) >> 7;
            smem[tok * K1_XCL_STR + e] = r[k];   // overwrite pre region (barriered)
        }
    }
    __syncthreads();

    // ---- Phase D1: B (rows 4..19) and C (rows 20..35) projections ----
    for (int i = tid; i < 64 * 32; i += 256) {
        int tok = i >> 5;
        int f = i & 31;
        const float4* xr = (const float4*)(smem + tok * K1_XCL_STR);
        const float4* wr = (const float4*)(xp_w + (4 + f) * 128);
        float acc = 0.f;
        #pragma unroll
        for (int q = 0; q < 32; ++q) {
            float4 a = xr[q], w4 = wr[q];
            acc += a.x*w4.x + a.y*w4.y + a.z*w4.z + a.w*w4.w;
        }
        size_t row = (size_t)(b * HW_ + l0 + tok);
        if (f < 16) Bm_g[row * 16 + f] = acc;
        else        Cm_g[row * 16 + (f - 16)] = acc;
    }
    // ---- Phase D2: dt projection (rows 0..3), one (token,r) per thread ----
    {
        int tok = tid >> 2;
        int rr = tid & 3;
        const float4* xr = (const float4*)(smem + tok * K1_XCL_STR);
        const float4* wr = (const float4*)(xp_w + rr * 128);
        float acc = 0.f;
        #pragma unroll
        for (int q = 0; q < 32; ++q) {
            float4 a = xr[q], w4 = wr[q];
            acc += a.x*w4.x + a.y*w4.y + a.z*w4.z + a.w*w4.w;
        }
        dtl[tid] = acc;
    }
    __syncthreads();
    // ---- Phase D3: delta = softplus(dt @ dt_w^T + dt_b) ----
    {
        const int e = tid & 127;
        float w0 = dt_w[e*4], w1 = dt_w[e*4+1], w2 = dt_w[e*4+2], w3 = dt_w[e*4+3];
        float bb = dt_b[e];
        #pragma unroll
        for (int k = 0; k < 32; ++k) {
            int tok = (tid + k * 256) >> 7;
            float4 dv = *(const float4*)(dtl + tok * 4);
            float v = bb + w0*dv.x + w1*dv.y + w2*dv.z + w3*dv.w;
            delta_g[((size_t)(b * HW_ + l0 + tok)) * 128 + e] = softplusf_(v);
        }
    }
}

// ---------------------------------------------------------------------------
// K2: spatial scan pass 1 — per-chunk summaries (cumulative dA product, local h)
// grid 512 (b*256 chunks), block 256: thread = (e, n-half), 8 states each
// ---------------------------------------------------------------------------
__global__ __launch_bounds__(256) void k2_scan1(
    const float* __restrict__ delta_g, const float* __restrict__ xc_g,
    const float* __restrict__ Bm_g, const float* __restrict__ A_log,
    float* __restrict__ cumA_g, float* __restrict__ hsum_g)
{
    const int tid = threadIdx.x;
    const int b = blockIdx.x >> 8;
    const int ch = blockIdx.x & 255;
    const int e = tid >> 1;
    const int n0 = (tid & 1) * 8;
    float A[8];
    #pragma unroll
    for (int j = 0; j < 8; ++j) A[j] = -__expf(A_log[e * 16 + n0 + j]);
    float h[8], cA[8];
    #pragma unroll
    for (int j = 0; j < 8; ++j) { h[j] = 0.f; cA[j] = 1.f; }
    const size_t rowbase = (size_t)b * HW_ + ch * SLC;
    for (int t = 0; t < SLC; ++t) {
        size_t row = rowbase + t;
        float d = delta_g[row * 128 + e];
        float u = xc_g[row * 128 + e];
        float4 b0 = *(const float4*)(Bm_g + row * 16 + n0);
        float4 b1 = *(const float4*)(Bm_g + row * 16 + n0 + 4);
        float Bv[8]; *(float4*)(Bv) = b0; *(float4*)(Bv + 4) = b1;
        float du = d * u;
        #pragma unroll
        for (int j = 0; j < 8; ++j) {
            float dA = __expf(d * A[j]);
            h[j] = h[j] * dA + du * Bv[j];
            cA[j] *= dA;
        }
    }
    size_t so = ((size_t)(b * SCH + ch)) * 2048 + tid * 8;
    #pragma unroll
    for (int j = 0; j < 8; ++j) { cumA_g[so + j] = cA[j]; hsum_g[so + j] = h[j]; }
}

// ---------------------------------------------------------------------------
// K3 v2: cross-chunk exclusive combine (4096 independent streams, 256 steps)
// 16-deep load batching: 32 loads in flight per round to hide HBM latency.
// ---------------------------------------------------------------------------
__global__ __launch_bounds__(256) void k3_combine(
    const float* __restrict__ cumA_g, const float* __restrict__ hsum_g,
    float* __restrict__ Hin_g)
{
    int gid = blockIdx.x * 256 + threadIdx.x;     // 0..4095
    int b = gid >> 11;
    int en = gid & 2047;
    float st = 0.f;
    size_t o = (size_t)b * SCH * 2048 + en;
    for (int cb = 0; cb < SCH; cb += 16) {
        float a[16], hs[16];
        #pragma unroll
        for (int k = 0; k < 16; ++k) {
            a[k]  = cumA_g[o + (size_t)k * 2048];
            hs[k] = hsum_g[o + (size_t)k * 2048];
        }
        #pragma unroll
        for (int k = 0; k < 16; ++k) {
            Hin_g[o + (size_t)k * 2048] = st;
            st = st * a[k] + hs[k];
        }
        o += (size_t)16 * 2048;
    }
}

// ---------------------------------------------------------------------------
// K4: spatial scan pass 2 + y gating + out_proj + NCHW store + GN partials
// grid 512, block 256
// ---------------------------------------------------------------------------
__global__ __launch_bounds__(256) void k4_scan2(
    const float* __restrict__ delta_g, const float* __restrict__ xc_g,
    const float* __restrict__ sz_g, const float* __restrict__ Bm_g,
    const float* __restrict__ Cm_g, const float* __restrict__ A_log,
    const float* __restrict__ Dp, const float* __restrict__ Hin_g,
    const float* __restrict__ out_w,
    float* __restrict__ spa_raw, float* __restrict__ part_spa)
{
    __shared__ float ytile[SLC * 128];   // y'(t,e)
    __shared__ float otile[64 * 65];     // out(c,t), padded
    __shared__ float wred[32];
    const int tid = threadIdx.x;
    const int b = blockIdx.x >> 8;
    const int ch = blockIdx.x & 255;
    const int e = tid >> 1;
    const int nh = tid & 1;
    const int n0 = nh * 8;
    float A[8];
    #pragma unroll
    for (int j = 0; j < 8; ++j) A[j] = -__expf(A_log[e * 16 + n0 + j]);
    float Dv = Dp[e];
    float h[8];
    size_t so = ((size_t)(b * SCH + ch)) * 2048 + tid * 8;
    #pragma unroll
    for (int j = 0; j < 8; ++j) h[j] = Hin_g[so + j];
    const size_t rowbase = (size_t)b * HW_ + ch * SLC;
    for (int t = 0; t < SLC; ++t) {
        size_t row = rowbase + t;
        float d = delta_g[row * 128 + e];
        float u = xc_g[row * 128 + e];
        float4 b0 = *(const float4*)(Bm_g + row * 16 + n0);
        float4 b1 = *(const float4*)(Bm_g + row * 16 + n0 + 4);
        float4 c0 = *(const float4*)(Cm_g + row * 16 + n0);
        float4 c1 = *(const float4*)(Cm_g + row * 16 + n0 + 4);
        float Bv[8]; *(float4*)(Bv) = b0; *(float4*)(Bv + 4) = b1;
        float Cv[8]; *(float4*)(Cv) = c0; *(float4*)(Cv + 4) = c1;
        float du = d * u;
        float y = 0.f;
        #pragma unroll
        for (int j = 0; j < 8; ++j) {
            float dA = __expf(d * A[j]);
            h[j] = h[j] * dA + du * Bv[j];
            y += h[j] * Cv[j];
        }
        y += __shfl_xor(y, 1, 64);          // combine both n-halves
        if (nh == 0) {
            float szv = sz_g[row * 128 + e];
            ytile[t * 128 + e] = (y + u * Dv) * szv;
        }
    }
    __syncthreads();
    // out_proj: out(c,t) = sum_e out_w[c][e] * y'(t,e)
    for (int i = tid; i < 64 * SLC; i += 256) {
        int c = i & 63, t = i >> 6;
        const float4* wr = (const float4*)(out_w + c * 128);
        const float4* yr = (const float4*)(ytile + t * 128);
        float acc = 0.f;
        #pragma unroll
        for (int q = 0; q < 32; ++q) {
            float4 w4 = wr[q], yv4 = yr[q];
            acc += w4.x*yv4.x + w4.y*yv4.y + w4.z*yv4.z + w4.w*yv4.w;
        }
        otile[c * 65 + t] = acc;
    }
    __syncthreads();
    for (int i = tid; i < 64 * SLC; i += 256) {
        int c = i >> 6, t = i & 63;
        spa_raw[((size_t)b * NC + c) * HW_ + ch * SLC + t] = otile[c * 65 + t];
    }
    // GroupNorm partial sums (4 groups of 16 channels)
    float s[4], s2[4];
    #pragma unroll
    for (int g = 0; g < 4; ++g) {
        float a = 0.f, a2 = 0.f;
        for (int i = tid; i < 1024; i += 256) {
            int c = 16 * g + (i >> 6), t = i & 63;
            float v = otile[c * 65 + t];
            a += v; a2 += v * v;
        }
        s[g] = a; s2[g] = a2;
    }
    #pragma unroll
    for (int g = 0; g < 4; ++g) {
        #pragma unroll
        for (int o = 1; o < 64; o <<= 1) {
            s[g]  += __shfl_xor(s[g], o, 64);
            s2[g] += __shfl_xor(s2[g], o, 64);
        }
    }
    if ((tid & 63) == 0) {
        int w = tid >> 6;
        #pragma unroll
        for (int g = 0; g < 4; ++g) { wred[w*8 + g*2] = s[g]; wred[w*8 + g*2 + 1] = s2[g]; }
    }
    __syncthreads();
    if (tid < 8)
        part_spa[blockIdx.x * 8 + tid] = wred[tid] + wred[8+tid] + wred[16+tid] + wred[24+tid];
}

// ---------------------------------------------------------------------------
// K5 v3: whole spectral mamba fused, shuffle-based, register weights.
// 16 lanes per pixel-sequence, 16 seq/block. grid 2048, block 256.
// launch_bounds (256,2): VGPR cap 256 -> NO scratch spill (v2's 552 MB
// spill traffic came from the (256,4) 64-VGPR cap).
// ---------------------------------------------------------------------------
__global__ __launch_bounds__(256, 2) void k5_spectral(
    const float* __restrict__ x, const float* __restrict__ in_w,
    const float* __restrict__ conv_w, const float* __restrict__ conv_b,
    const float* __restrict__ xp_w, const float* __restrict__ dt_w,
    const float* __restrict__ dt_b, const float* __restrict__ A_log,
    const float* __restrict__ Dp, const float* __restrict__ out_w,
    float* __restrict__ spe_raw, float* __restrict__ part_spe)
{
    __shared__ float xin[16 * 65];    // [seq][c]
    __shared__ float ys[16 * 136];    // [seq][t*17+e]
    __shared__ float outs[64 * 17];   // [c][seq]
    __shared__ float wred[32];
    const int tid = threadIdx.x;
    const int b = blockIdx.x >> 10;
    const int hw0 = (blockIdx.x & 1023) << 4;
    const int s = tid >> 4;       // sequence in block (0..15)
    const int l = tid & 15;       // inner-channel e / state n role (0..15)
    const int base = tid & 48;    // 16-lane group base within wave

    for (int i = tid; i < 1024; i += 256) {
        int c = i >> 4, j = i & 15;
        xin[j * 65 + c] = x[((size_t)b * NC + c) * HW_ + hw0 + j];
    }

    // ---- hoist weights into registers ----
    float wdt[16];
    #pragma unroll
    for (int e = 0; e < 16; ++e) wdt[e] = xp_w[e];           // dt row (uniform)
    float wi0[8], wi1[8];
    #pragma unroll
    for (int c = 0; c < 8; ++c) { wi0[c] = in_w[l*8 + c]; wi1[c] = in_w[(l+16)*8 + c]; }
    float cw0 = conv_w[l*4], cw1 = conv_w[l*4+1], cw2 = conv_w[l*4+2], cw3 = conv_w[l*4+3];
    float cb = conv_b[l];
    float dtw = dt_w[l], dtb = dt_b[l];
    __syncthreads();

    // ---- in_proj: pre-conv xc + silu(z), all in registers ----
    float pre[8], sz[8];
    #pragma unroll
    for (int t = 0; t < 8; ++t) {
        float a0 = 0.f, a1 = 0.f;
        #pragma unroll
        for (int c = 0; c < 8; ++c) {
            float xv = xin[s * 65 + t * 8 + c];
            a0 += wi0[c] * xv; a1 += wi1[c] * xv;
        }
        pre[t] = a0; sz[t] = siluf_(a1);
    }
    // ---- causal depthwise conv along t (registers) ----
    float xcv[8];
    #pragma unroll
    for (int t = 0; t < 8; ++t) {
        float v = cb + cw3 * pre[t];
        if (t >= 1) v += cw2 * pre[t-1];
        if (t >= 2) v += cw1 * pre[t-2];
        if (t >= 3) v += cw0 * pre[t-3];
        xcv[t] = siluf_(v);
    }

    // ---- x-projections via shuffle broadcast of xcv across the 16-lane group.
    //      lane l computes B_n=l, C_n=l rows; dt row is lane-redundant. ----
    float wB[16], wC[16];
    #pragma unroll
    for (int e = 0; e < 16; ++e) {
        wB[e] = xp_w[(1 + l) * 16 + e];
        wC[e] = xp_w[(17 + l) * 16 + e];
    }
    float bn[8], cn[8], del[8];
    #pragma unroll
    for (int t = 0; t < 8; ++t) {
        float b_ = 0.f, c_ = 0.f, d0 = 0.f;
        #pragma unroll
        for (int e = 0; e < 16; ++e) {
            float xv = __shfl(xcv[t], base + e, 64);
            b_ += wB[e] * xv; c_ += wC[e] * xv; d0 += wdt[e] * xv;
        }
        bn[t] = b_; cn[t] = c_;
        del[t] = softplusf_(d0 * dtw + dtb);
    }

    // ---- selective scan, 16 states per lane, B/C gathered via shuffle ----
    float A[16];
    #pragma unroll
    for (int n = 0; n < 16; ++n) A[n] = -__expf(A_log[l * 16 + n]);
    float Dv = Dp[l];
    float h[16];
    #pragma unroll
    for (int n = 0; n < 16; ++n) h[n] = 0.f;
    #pragma unroll
    for (int t = 0; t < 8; ++t) {
        float d = del[t], u = xcv[t];
        float du = d * u;
        float y = 0.f;
        #pragma unroll
        for (int n = 0; n < 16; ++n) {
            float Bn = __shfl(bn[t], base + n, 64);
            float Cn = __shfl(cn[t], base + n, 64);
            float dA = __expf(d * A[n]);
            h[n] = h[n] * dA + du * Bn;
            y += h[n] * Cn;
        }
        ys[s * 136 + t * 17 + l] = (y + u * Dv) * sz[t];
    }
    __syncthreads();

    // ---- out_proj: 64 outputs per sequence (8 t x 8 d), 4 per lane ----
    {
        int t = l >> 1;
        int db = (l & 1) * 4;
        #pragma unroll
        for (int jj = 0; jj < 4; ++jj) {
            int dd = db + jj;
            float acc = 0.f;
            #pragma unroll
            for (int e = 0; e < 16; ++e) acc += out_w[dd * 16 + e] * ys[s * 136 + t * 17 + e];
            outs[(t * 8 + dd) * 17 + s] = acc;   // channel c = t*8+dd
        }
    }
    __syncthreads();

    // ---- coalesced NCHW store + GroupNorm partials (iteration k == group g) ----
    float sg[4], sg2[4];
    #pragma unroll
    for (int k = 0; k < 4; ++k) {
        int i = tid + k * 256;
        int c = i >> 4, j = i & 15;
        float v = outs[c * 17 + j];
        spe_raw[((size_t)b * NC + c) * HW_ + hw0 + j] = v;
        sg[k] = v; sg2[k] = v * v;
    }
    #pragma unroll
    for (int k = 0; k < 4; ++k) {
        #pragma unroll
        for (int o = 1; o < 64; o <<= 1) {
            sg[k]  += __shfl_xor(sg[k], o, 64);
            sg2[k] += __shfl_xor(sg2[k], o, 64);
        }
    }
    if ((tid & 63) == 0) {
        int w = tid >> 6;
        #pragma unroll
        for (int k = 0; k < 4; ++k) { wred[w*8 + k*2] = sg[k]; wred[w*8 + k*2 + 1] = sg2[k]; }
    }
    __syncthreads();
    if (tid < 8)
        part_spe[blockIdx.x * 8 + tid] = wred[tid] + wred[8+tid] + wred[16+tid] + wred[24+tid];
}

// ---------------------------------------------------------------------------
// K5b: reduce GN partials -> (mean, rstd) for 2 branches x 2 b x 4 groups
// ---------------------------------------------------------------------------
__global__ __launch_bounds__(256) void k5b_stats(
    const float* __restrict__ part_spa, const float* __restrict__ part_spe,
    float* __restrict__ stats)
{
    __shared__ float r1[256];
    __shared__ float fin[32];
    const int tid = threadIdx.x;
    const int combo = tid >> 4, sl = tid & 15;      // combo = b*8 + g*2 + st
    const int bb = combo >> 3, g = (combo >> 1) & 3, st = combo & 1;
    float acc = 0.f;
    for (int k = 0; k < 16; ++k)
        acc += part_spa[(bb * 256 + sl * 16 + k) * 8 + g * 2 + st];
    r1[tid] = acc;
    __syncthreads();
    if (tid < 16) { float a = 0.f; for (int k = 0; k < 16; ++k) a += r1[tid*16 + k]; fin[tid] = a; }
    __syncthreads();
    acc = 0.f;
    for (int k = 0; k < 64; ++k)
        acc += part_spe[(bb * 1024 + sl * 64 + k) * 8 + g * 2 + st];
    r1[tid] = acc;
    __syncthreads();
    if (tid < 16) { float a = 0.f; for (int k = 0; k < 16; ++k) a += r1[tid*16 + k]; fin[16 + tid] = a; }
    __syncthreads();
    if (tid < 16) {
        float S  = fin[(tid >> 3) * 16 + (tid & 7) * 2];
        float S2 = fin[(tid >> 3) * 16 + (tid & 7) * 2 + 1];
        const float N = 262144.f;     // 16 channels * 16384 positions
        float mu = S / N;
        float var = S2 / N - mu * mu;
        stats[tid * 2] = mu;
        stats[tid * 2 + 1] = rsqrtf(var + 1e-5f);
    }
}

// ---------------------------------------------------------------------------
// K6: GN-normalize + silu + residual for both branches, softmax fuse, store
// ---------------------------------------------------------------------------
__global__ __launch_bounds__(256) void k6_fuse(
    const float* __restrict__ x, const float* __restrict__ spa_raw,
    const float* __restrict__ spe_raw, const float* __restrict__ stats,
    const float* __restrict__ gwa, const float* __restrict__ gba,
    const float* __restrict__ gwe, const float* __restrict__ gbe,
    const float* __restrict__ fw, float* __restrict__ out)
{
    size_t i4 = (size_t)blockIdx.x * 256 + threadIdx.x;
    size_t base = i4 * 4;
    int b = (int)(base >> 20);
    int rem = (int)(base & 1048575);
    int c = rem >> 14;
    int g = c >> 4;
    int sidx = (b * 4 + g) * 2;
    float ma = stats[sidx],      ra = stats[sidx + 1];
    float me = stats[16 + sidx], re = stats[16 + sidx + 1];
    float wa = gwa[c], ba = gba[c], we = gwe[c], be = gbe[c];
    float f0 = fw[0], f1 = fw[1];
    float mx = fmaxf(f0, f1);
    float e0 = __expf(f0 - mx), e1 = __expf(f1 - mx);
    float inv = 1.f / (e0 + e1);
    float w0 = e0 * inv, w1 = e1 * inv;
    float4 xv = *(const float4*)(x + base);
    float4 av = *(const float4*)(spa_raw + base);
    float4 ev = *(const float4*)(spe_raw + base);
    float xr[4] = {xv.x, xv.y, xv.z, xv.w};
    float ar[4] = {av.x, av.y, av.z, av.w};
    float er[4] = {ev.x, ev.y, ev.z, ev.w};
    float orr[4];
    #pragma unroll
    for (int k = 0; k < 4; ++k) {
        float spa = siluf_((ar[k] - ma) * ra * wa + ba) + xr[k];
        float spe = siluf_((er[k] - me) * re * we + be) + xr[k];
        orr[k] = spa * w0 + spe * w1 + xr[k];
    }
    float4 ov = {orr[0], orr[1], orr[2], orr[3]};
    *(float4*)(out + base) = ov;
}

// ---------------------------------------------------------------------------
extern "C" void kernel_launch(void* const* d_in, const int* in_sizes, int n_in,
                              void* d_out, int out_size, void* d_ws, size_t ws_size,
                              hipStream_t stream)
{
    const float* x      = (const float*)d_in[0];
    const float* a_inw  = (const float*)d_in[1];
    const float* a_cw   = (const float*)d_in[2];
    const float* a_cb   = (const float*)d_in[3];
    const float* a_xp   = (const float*)d_in[4];
    const float* a_dtw  = (const float*)d_in[5];
    const float* a_dtb  = (const float*)d_in[6];
    const float* a_Alog = (const float*)d_in[7];
    const float* a_D    = (const float*)d_in[8];
    const float* a_ow   = (const float*)d_in[9];
    const float* e_inw  = (const float*)d_in[10];
    const float* e_cw   = (const float*)d_in[11];
    const float* e_cb   = (const float*)d_in[12];
    const float* e_xp   = (const float*)d_in[13];
    const float* e_dtw  = (const float*)d_in[14];
    const float* e_dtb  = (const float*)d_in[15];
    const float* e_Alog = (const float*)d_in[16];
    const float* e_D    = (const float*)d_in[17];
    const float* e_ow   = (const float*)d_in[18];
    const float* gwa    = (const float*)d_in[19];
    const float* gba    = (const float*)d_in[20];
    const float* gwe    = (const float*)d_in[21];
    const float* gbe    = (const float*)d_in[22];
    const float* fw     = (const float*)d_in[23];

    float* ws    = (float*)d_ws;
    float* xc    = ws;                    // 32768*128
    float* sz    = xc    + 4194304;       // 32768*128
    float* delta = sz    + 4194304;       // 32768*128
    float* Bm    = delta + 4194304;       // 32768*16
    float* Cm    = Bm    + 524288;        // 32768*16
    float* cumA  = Cm    + 524288;        // 2*256*2048
    float* hsum  = cumA  + 1048576;
    float* Hin   = hsum  + 1048576;
    float* spa_r = Hin   + 1048576;       // 2*64*16384
    float* spe_r = spa_r + 2097152;
    float* pspa  = spe_r + 2097152;       // 512*8
    float* pspe  = pspa  + 4096;          // 2048*8
    float* stats = pspe  + 16384;         // 32

    k1_spatial_pre<<<512, 256, 0, stream>>>(x, a_inw, a_cw, a_cb, a_xp, a_dtw, a_dtb,
                                            xc, sz, delta, Bm, Cm);
    k2_scan1<<<512, 256, 0, stream>>>(delta, xc, Bm, a_Alog, cumA, hsum);
    k3_combine<<<16, 256, 0, stream>>>(cumA, hsum, Hin);
    k5_spectral<<<2048, 256, 0, stream>>>(x, e_inw, e_cw, e_cb, e_xp, e_dtw, e_dtb,
                                          e_Alog, e_D, e_ow, spe_r, pspe);
    k4_scan2<<<512, 256, 0, stream>>>(delta, xc, sz, Bm, Cm, a_Alog, a_D, Hin, a_ow,
                                      spa_r, pspa);
    k5b_stats<<<1, 256, 0, stream>>>(pspa, pspe, stats);
    k6_fuse<<<2048, 256, 0, stream>>>(x, spa_r, spe_r, stats, gwa, gba, gwe, gbe, fw,
                                      (float*)d_out);
}

// Round 4
// 413.356 us; speedup vs baseline: 1.4760x; 1.0601x over previous
//
#include <hip/hip_runtime.h>
#include <math.h>

// ---------------------------------------------------------------------------
// Problem constants
//   x: (B=2, C=64, H=128, W=128) fp32, HW = 16384 tokens per batch
//   spatial mamba: d_model=64, d_inner=128, dt_rank=4, d_state=16, L=16384
//   spectral mamba: per-pixel sequence of TOKEN=8 over channel groups of 8,
//                   d_model=8, d_inner=16, dt_rank=1, d_state=16
// ---------------------------------------------------------------------------

#define NB 2
#define NC 64
#define HW_ 16384
#define SCH 512          // spatial scan chunks per batch
#define SLC 32           // tokens per chunk (16384/512)

__device__ __forceinline__ float sigmoidf_(float v) { return 1.f / (1.f + __expf(-v)); }
__device__ __forceinline__ float siluf_(float v)    { return v * sigmoidf_(v); }
__device__ __forceinline__ float softplusf_(float v) {
    return v > 0.f ? v + log1pf(__expf(-v)) : log1pf(__expf(v));
}

// ---------------------------------------------------------------------------
// K1: spatial in_proj + depthwise causal conv + silu + x-proj(B,C,dt)
// grid 512 (= 2 b * 256 tiles of 64 tokens), block 256
// Outputs: xc [tok][128], silu(z) [tok][128], dt-proj [tok][4], B/C [tok][16]
// ---------------------------------------------------------------------------
#define K1_XS_OFF 8576       // floats; pre/xcl region is [0, 8576)
#define K1_XS_STR 68         // x tile row stride (4-aligned, bank-rotating)
#define K1_XCL_STR 132       // conv-output tile row stride

__global__ __launch_bounds__(256) void k1_spatial_pre(
    const float* __restrict__ x, const float* __restrict__ in_w,
    const float* __restrict__ conv_w, const float* __restrict__ conv_b,
    const float* __restrict__ xp_w,
    float* __restrict__ xc_g, float* __restrict__ sz_g,
    float* __restrict__ dtp_g, float* __restrict__ Bm_g, float* __restrict__ Cm_g)
{
    __shared__ float smem[13132];   // 8576 (pre/xcl) + 67*68 (x tile)
    const int tid = threadIdx.x;
    const int b   = blockIdx.x >> 8;
    const int l0  = (blockIdx.x & 255) << 6;

    // ---- Phase A: load x tile, tokens l0-3 .. l0+63, layout [tok][c] ----
    for (int i = tid; i < 67 * 64; i += 256) {
        int c = i / 67;
        int tok = i - c * 67;
        int l = l0 + tok - 3;
        float v = (l >= 0) ? x[((size_t)b * NC + c) * HW_ + l] : 0.f;
        smem[K1_XS_OFF + tok * K1_XS_STR + c] = v;
    }
    __syncthreads();

    // ---- Phase B: in_proj (256x64 matvec per token), weights in VGPRs ----
    {
        const int e = tid & 127;
        const int half = tid >> 7;
        float w[64];
        #pragma unroll
        for (int q = 0; q < 16; ++q) {
            float4 wv = *(const float4*)(in_w + e * 64 + q * 4);
            w[q*4] = wv.x; w[q*4+1] = wv.y; w[q*4+2] = wv.z; w[q*4+3] = wv.w;
        }
        int t0 = half ? 34 : 0, t1 = half ? 67 : 34;
        for (int tok = t0; tok < t1; ++tok) {
            const float4* xr = (const float4*)(smem + K1_XS_OFF + tok * K1_XS_STR);
            float acc = 0.f;
            #pragma unroll
            for (int q = 0; q < 16; ++q) {
                float4 xv = xr[q];
                acc += w[q*4]*xv.x + w[q*4+1]*xv.y + w[q*4+2]*xv.z + w[q*4+3]*xv.w;
            }
            smem[tok * 128 + e] = acc;      // pre-conv activation
        }
        #pragma unroll
        for (int q = 0; q < 16; ++q) {
            float4 wv = *(const float4*)(in_w + (128 + e) * 64 + q * 4);
            w[q*4] = wv.x; w[q*4+1] = wv.y; w[q*4+2] = wv.z; w[q*4+3] = wv.w;
        }
        int z0 = half * 32;
        for (int tok = z0; tok < z0 + 32; ++tok) {
            const float4* xr = (const float4*)(smem + K1_XS_OFF + (tok + 3) * K1_XS_STR);
            float acc = 0.f;
            #pragma unroll
            for (int q = 0; q < 16; ++q) {
                float4 xv = xr[q];
                acc += w[q*4]*xv.x + w[q*4+1]*xv.y + w[q*4+2]*xv.z + w[q*4+3]*xv.w;
            }
            sz_g[((size_t)(b * HW_ + l0 + tok)) * 128 + e] = siluf_(acc);  // silu(z)
        }
    }
    __syncthreads();

    // ---- Phase C: depthwise causal conv (k=4) + bias + silu ----
    {
        const int e = tid & 127;
        float cw0 = conv_w[e*4], cw1 = conv_w[e*4+1], cw2 = conv_w[e*4+2], cw3 = conv_w[e*4+3];
        float cb = conv_b[e];
        float r[32];
        #pragma unroll
        for (int k = 0; k < 32; ++k) {
            int tok = (tid + k * 256) >> 7;
            float v = cb + cw0 * smem[(tok+0)*128 + e] + cw1 * smem[(tok+1)*128 + e]
                         + cw2 * smem[(tok+2)*128 + e] + cw3 * smem[(tok+3)*128 + e];
            v = siluf_(v);
            r[k] = v;
            xc_g[((size_t)(b * HW_ + l0 + tok)) * 128 + e] = v;
        }
        __syncthreads();
        #pragma unroll
        for (int k = 0; k < 32; ++k) {
            int tok = (tid + k * 256) >> 7;
            smem[tok * K1_XCL_STR + e] = r[k];   // overwrite pre region (barriered)
        }
    }
    __syncthreads();

    // ---- Phase D1: B (rows 4..19) and C (rows 20..35) projections ----
    for (int i = tid; i < 64 * 32; i += 256) {
        int tok = i >> 5;
        int f = i & 31;
        const float4* xr = (const float4*)(smem + tok * K1_XCL_STR);
        const float4* wr = (const float4*)(xp_w + (4 + f) * 128);
        float acc = 0.f;
        #pragma unroll
        for (int q = 0; q < 32; ++q) {
            float4 a = xr[q], w4 = wr[q];
            acc += a.x*w4.x + a.y*w4.y + a.z*w4.z + a.w*w4.w;
        }
        size_t row = (size_t)(b * HW_ + l0 + tok);
        if (f < 16) Bm_g[row * 16 + f] = acc;
        else        Cm_g[row * 16 + (f - 16)] = acc;
    }
    // ---- Phase D2: dt projection (rows 0..3), one (token,r) per thread ----
    {
        int tok = tid >> 2;
        int rr = tid & 3;
        const float4* xr = (const float4*)(smem + tok * K1_XCL_STR);
        const float4* wr = (const float4*)(xp_w + rr * 128);
        float acc = 0.f;
        #pragma unroll
        for (int q = 0; q < 32; ++q) {
            float4 a = xr[q], w4 = wr[q];
            acc += a.x*w4.x + a.y*w4.y + a.z*w4.z + a.w*w4.w;
        }
        dtp_g[(size_t)(b * HW_ + l0) * 4 + tid] = acc;   // coalesced: (l0+tok)*4+rr
    }
}

// ---------------------------------------------------------------------------
// K2 v3: spatial scan pass 1 — per-chunk summaries, LDS-staged inputs.
// grid 1024 (b*512 chunks), block 256: thread = (e, n-half), 8 states each.
// Chunk inputs staged coalesced into LDS; scan loop is pure LDS+VALU.
// ---------------------------------------------------------------------------
__global__ __launch_bounds__(256) void k2_scan1(
    const float* __restrict__ xc_g, const float* __restrict__ Bm_g,
    const float* __restrict__ dtp_g, const float* __restrict__ dt_w,
    const float* __restrict__ dt_b, const float* __restrict__ A_log,
    float* __restrict__ cumA_g, float* __restrict__ hsum_g)
{
    __shared__ float su[SLC * 128];   // xc chunk
    __shared__ float sB[SLC * 16];
    __shared__ float sdt[SLC * 4];
    const int tid = threadIdx.x;
    const int b = blockIdx.x >> 9;
    const int ch = blockIdx.x & 511;
    const size_t rowbase = (size_t)b * HW_ + ch * SLC;

    const float4* u4 = (const float4*)(xc_g + rowbase * 128);
    #pragma unroll
    for (int j = 0; j < 4; ++j) ((float4*)su)[tid + j * 256] = u4[tid + j * 256];
    if (tid < 128) ((float4*)sB)[tid] = ((const float4*)(Bm_g + rowbase * 16))[tid];
    if (tid < 32)  ((float4*)sdt)[tid] = ((const float4*)(dtp_g + rowbase * 4))[tid];

    const int e = tid >> 1;
    const int n0 = (tid & 1) * 8;
    float A[8];
    #pragma unroll
    for (int j = 0; j < 8; ++j) A[j] = -__expf(A_log[e * 16 + n0 + j]);
    float4 wdt = *(const float4*)(dt_w + e * 4);
    float dtb = dt_b[e];
    float h[8], cA[8];
    #pragma unroll
    for (int j = 0; j < 8; ++j) { h[j] = 0.f; cA[j] = 1.f; }
    __syncthreads();

    for (int t = 0; t < SLC; ++t) {
        float4 dv = *(const float4*)(sdt + t * 4);
        float d = softplusf_(wdt.x*dv.x + wdt.y*dv.y + wdt.z*dv.z + wdt.w*dv.w + dtb);
        float u = su[t * 128 + e];
        float4 b0 = *(const float4*)(sB + t * 16 + n0);
        float4 b1 = *(const float4*)(sB + t * 16 + n0 + 4);
        float Bv[8]; *(float4*)(Bv) = b0; *(float4*)(Bv + 4) = b1;
        float du = d * u;
        #pragma unroll
        for (int j = 0; j < 8; ++j) {
            float dA = __expf(d * A[j]);
            h[j] = h[j] * dA + du * Bv[j];
            cA[j] *= dA;
        }
    }
    size_t so = (size_t)blockIdx.x * 2048 + tid * 8;
    *(float4*)(cumA_g + so)     = *(float4*)(cA);
    *(float4*)(cumA_g + so + 4) = *(float4*)(cA + 4);
    *(float4*)(hsum_g + so)     = *(float4*)(h);
    *(float4*)(hsum_g + so + 4) = *(float4*)(h + 4);
}

// ---------------------------------------------------------------------------
// K3: cross-chunk exclusive combine (4096 independent streams, 512 steps)
// 16-deep load batching: 32 loads in flight per round to hide HBM latency.
// ---------------------------------------------------------------------------
__global__ __launch_bounds__(256) void k3_combine(
    const float* __restrict__ cumA_g, const float* __restrict__ hsum_g,
    float* __restrict__ Hin_g)
{
    int gid = blockIdx.x * 256 + threadIdx.x;     // 0..4095
    int b = gid >> 11;
    int en = gid & 2047;
    float st = 0.f;
    size_t o = (size_t)b * SCH * 2048 + en;
    for (int cb = 0; cb < SCH; cb += 16) {
        float a[16], hs[16];
        #pragma unroll
        for (int k = 0; k < 16; ++k) {
            a[k]  = cumA_g[o + (size_t)k * 2048];
            hs[k] = hsum_g[o + (size_t)k * 2048];
        }
        #pragma unroll
        for (int k = 0; k < 16; ++k) {
            Hin_g[o + (size_t)k * 2048] = st;
            st = st * a[k] + hs[k];
        }
        o += (size_t)16 * 2048;
    }
}

// ---------------------------------------------------------------------------
// K4 v3: spatial scan pass 2 + gating + out_proj + NCHW store + GN partials.
// grid 1024, block 256. All chunk inputs LDS-staged; sz applied in a
// coalesced post-pass; otile overlays su after the scan. LDS = 37.5 KB.
// ---------------------------------------------------------------------------
__global__ __launch_bounds__(256) void k4_scan2(
    const float* __restrict__ xc_g, const float* __restrict__ sz_g,
    const float* __restrict__ Bm_g, const float* __restrict__ Cm_g,
    const float* __restrict__ dtp_g, const float* __restrict__ dt_w,
    const float* __restrict__ dt_b, const float* __restrict__ A_log,
    const float* __restrict__ Dp, const float* __restrict__ Hin_g,
    const float* __restrict__ out_w,
    float* __restrict__ spa_raw, float* __restrict__ part_spa)
{
    __shared__ float lds[9344];
    float* su  = lds;               // 4096: xc chunk [t][e]
    float* sB  = lds + 4096;        // 512
    float* sC  = lds + 4608;        // 512
    float* sdt = lds + 5120;        // 128
    float* yt  = lds + 5248;        // 4096: y'(t,e)
    float* ot  = lds;               // 2112: out(c,t) — overlays su post-scan
    __shared__ float wred[32];
    const int tid = threadIdx.x;
    const int b = blockIdx.x >> 9;
    const int ch = blockIdx.x & 511;
    const size_t rowbase = (size_t)b * HW_ + ch * SLC;

    const float4* u4 = (const float4*)(xc_g + rowbase * 128);
    #pragma unroll
    for (int j = 0; j < 4; ++j) ((float4*)su)[tid + j * 256] = u4[tid + j * 256];
    if (tid < 128) ((float4*)sB)[tid] = ((const float4*)(Bm_g + rowbase * 16))[tid];
    else           ((float4*)sC)[tid - 128] = ((const float4*)(Cm_g + rowbase * 16))[tid - 128];
    if (tid < 32)  ((float4*)sdt)[tid] = ((const float4*)(dtp_g + rowbase * 4))[tid];

    const int e = tid >> 1;
    const int nh = tid & 1;
    const int n0 = nh * 8;
    float A[8];
    #pragma unroll
    for (int j = 0; j < 8; ++j) A[j] = -__expf(A_log[e * 16 + n0 + j]);
    float4 wdt = *(const float4*)(dt_w + e * 4);
    float dtb = dt_b[e];
    float Dv = Dp[e];
    float h[8];
    size_t so = (size_t)blockIdx.x * 2048 + tid * 8;
    *(float4*)(h)     = *(const float4*)(Hin_g + so);
    *(float4*)(h + 4) = *(const float4*)(Hin_g + so + 4);
    __syncthreads();

    for (int t = 0; t < SLC; ++t) {
        float4 dv = *(const float4*)(sdt + t * 4);
        float d = softplusf_(wdt.x*dv.x + wdt.y*dv.y + wdt.z*dv.z + wdt.w*dv.w + dtb);
        float u = su[t * 128 + e];
        float4 b0 = *(const float4*)(sB + t * 16 + n0);
        float4 b1 = *(const float4*)(sB + t * 16 + n0 + 4);
        float4 c0 = *(const float4*)(sC + t * 16 + n0);
        float4 c1 = *(const float4*)(sC + t * 16 + n0 + 4);
        float Bv[8]; *(float4*)(Bv) = b0; *(float4*)(Bv + 4) = b1;
        float Cv[8]; *(float4*)(Cv) = c0; *(float4*)(Cv + 4) = c1;
        float du = d * u;
        float y = 0.f;
        #pragma unroll
        for (int j = 0; j < 8; ++j) {
            float dA = __expf(d * A[j]);
            h[j] = h[j] * dA + du * Bv[j];
            y += h[j] * Cv[j];
        }
        y += __shfl_xor(y, 1, 64);          // combine both n-halves
        if (nh == 0) yt[t * 128 + e] = y + u * Dv;
    }
    __syncthreads();

    // ---- gate pass: yt *= silu(z), coalesced float4 global reads ----
    {
        const float4* sz4 = (const float4*)(sz_g + rowbase * 128);
        #pragma unroll
        for (int j = 0; j < 4; ++j) {
            int f = tid + j * 256;
            float4 yv = ((float4*)yt)[f];
            float4 sv = sz4[f];
            yv.x *= sv.x; yv.y *= sv.y; yv.z *= sv.z; yv.w *= sv.w;
            ((float4*)yt)[f] = yv;
        }
    }
    __syncthreads();

    // ---- out_proj: out(c,t) = sum_e out_w[c][e] * y'(t,e) ----
    for (int i = tid; i < 64 * SLC; i += 256) {
        int c = i & 63, t = i >> 6;
        const float4* wr = (const float4*)(out_w + c * 128);
        const float4* yr = (const float4*)(yt + t * 128);
        float acc = 0.f;
        #pragma unroll
        for (int q = 0; q < 32; ++q) {
            float4 w4 = wr[q], yv4 = yr[q];
            acc += w4.x*yv4.x + w4.y*yv4.y + w4.z*yv4.z + w4.w*yv4.w;
        }
        ot[c * 33 + t] = acc;
    }
    __syncthreads();

    // ---- NCHW store ----
    for (int i = tid; i < 64 * SLC; i += 256) {
        int c = i >> 5, t = i & 31;
        spa_raw[((size_t)b * NC + c) * HW_ + ch * SLC + t] = ot[c * 33 + t];
    }
    // ---- GroupNorm partial sums (4 groups of 16 channels) ----
    float s[4], s2[4];
    #pragma unroll
    for (int g = 0; g < 4; ++g) {
        float a = 0.f, a2 = 0.f;
        for (int i = tid; i < 512; i += 256) {
            int c = 16 * g + (i >> 5), t = i & 31;
            float v = ot[c * 33 + t];
            a += v; a2 += v * v;
        }
        s[g] = a; s2[g] = a2;
    }
    #pragma unroll
    for (int g = 0; g < 4; ++g) {
        #pragma unroll
        for (int o = 1; o < 64; o <<= 1) {
            s[g]  += __shfl_xor(s[g], o, 64);
            s2[g] += __shfl_xor(s2[g], o, 64);
        }
    }
    if ((tid & 63) == 0) {
        int w = tid >> 6;
        #pragma unroll
        for (int g = 0; g < 4; ++g) { wred[w*8 + g*2] = s[g]; wred[w*8 + g*2 + 1] = s2[g]; }
    }
    __syncthreads();
    if (tid < 8)
        part_spa[blockIdx.x * 8 + tid] = wred[tid] + wred[8+tid] + wred[16+tid] + wred[24+tid];
}

// ---------------------------------------------------------------------------
// K5 v3: whole spectral mamba fused, shuffle-based, register weights.
// 16 lanes per pixel-sequence, 16 seq/block. grid 2048, block 256.
// ---------------------------------------------------------------------------
__global__ __launch_bounds__(256, 2) void k5_spectral(
    const float* __restrict__ x, const float* __restrict__ in_w,
    const float* __restrict__ conv_w, const float* __restrict__ conv_b,
    const float* __restrict__ xp_w, const float* __restrict__ dt_w,
    const float* __restrict__ dt_b, const float* __restrict__ A_log,
    const float* __restrict__ Dp, const float* __restrict__ out_w,
    float* __restrict__ spe_raw, float* __restrict__ part_spe)
{
    __shared__ float xin[16 * 65];    // [seq][c]
    __shared__ float ys[16 * 136];    // [seq][t*17+e]
    __shared__ float outs[64 * 17];   // [c][seq]
    __shared__ float wred[32];
    const int tid = threadIdx.x;
    const int b = blockIdx.x >> 10;
    const int hw0 = (blockIdx.x & 1023) << 4;
    const int s = tid >> 4;       // sequence in block (0..15)
    const int l = tid & 15;       // inner-channel e / state n role (0..15)
    const int base = tid & 48;    // 16-lane group base within wave

    for (int i = tid; i < 1024; i += 256) {
        int c = i >> 4, j = i & 15;
        xin[j * 65 + c] = x[((size_t)b * NC + c) * HW_ + hw0 + j];
    }

    // ---- hoist weights into registers ----
    float wdt[16];
    #pragma unroll
    for (int e = 0; e < 16; ++e) wdt[e] = xp_w[e];           // dt row (uniform)
    float wi0[8], wi1[8];
    #pragma unroll
    for (int c = 0; c < 8; ++c) { wi0[c] = in_w[l*8 + c]; wi1[c] = in_w[(l+16)*8 + c]; }
    float cw0 = conv_w[l*4], cw1 = conv_w[l*4+1], cw2 = conv_w[l*4+2], cw3 = conv_w[l*4+3];
    float cb = conv_b[l];
    float dtw = dt_w[l], dtb = dt_b[l];
    __syncthreads();

    // ---- in_proj: pre-conv xc + silu(z), all in registers ----
    float pre[8], sz[8];
    #pragma unroll
    for (int t = 0; t < 8; ++t) {
        float a0 = 0.f, a1 = 0.f;
        #pragma unroll
        for (int c = 0; c < 8; ++c) {
            float xv = xin[s * 65 + t * 8 + c];
            a0 += wi0[c] * xv; a1 += wi1[c] * xv;
        }
        pre[t] = a0; sz[t] = siluf_(a1);
    }
    // ---- causal depthwise conv along t (registers) ----
    float xcv[8];
    #pragma unroll
    for (int t = 0; t < 8; ++t) {
        float v = cb + cw3 * pre[t];
        if (t >= 1) v += cw2 * pre[t-1];
        if (t >= 2) v += cw1 * pre[t-2];
        if (t >= 3) v += cw0 * pre[t-3];
        xcv[t] = siluf_(v);
    }

    // ---- x-projections via shuffle broadcast of xcv across the 16-lane group.
    //      lane l computes B_n=l, C_n=l rows; dt row is lane-redundant. ----
    float wB[16], wC[16];
    #pragma unroll
    for (int e = 0; e < 16; ++e) {
        wB[e] = xp_w[(1 + l) * 16 + e];
        wC[e] = xp_w[(17 + l) * 16 + e];
    }
    float bn[8], cn[8], del[8];
    #pragma unroll
    for (int t = 0; t < 8; ++t) {
        float b_ = 0.f, c_ = 0.f, d0 = 0.f;
        #pragma unroll
        for (int e = 0; e < 16; ++e) {
            float xv = __shfl(xcv[t], base + e, 64);
            b_ += wB[e] * xv; c_ += wC[e] * xv; d0 += wdt[e] * xv;
        }
        bn[t] = b_; cn[t] = c_;
        del[t] = softplusf_(d0 * dtw + dtb);
    }

    // ---- selective scan, 16 states per lane, B/C gathered via shuffle ----
    float A[16];
    #pragma unroll
    for (int n = 0; n < 16; ++n) A[n] = -__expf(A_log[l * 16 + n]);
    float Dv = Dp[l];
    float h[16];
    #pragma unroll
    for (int n = 0; n < 16; ++n) h[n] = 0.f;
    #pragma unroll
    for (int t = 0; t < 8; ++t) {
        float d = del[t], u = xcv[t];
        float du = d * u;
        float y = 0.f;
        #pragma unroll
        for (int n = 0; n < 16; ++n) {
            float Bn = __shfl(bn[t], base + n, 64);
            float Cn = __shfl(cn[t], base + n, 64);
            float dA = __expf(d * A[n]);
            h[n] = h[n] * dA + du * Bn;
            y += h[n] * Cn;
        }
        ys[s * 136 + t * 17 + l] = (y + u * Dv) * sz[t];
    }
    __syncthreads();

    // ---- out_proj: 64 outputs per sequence (8 t x 8 d), 4 per lane ----
    {
        int t = l >> 1;
        int db = (l & 1) * 4;
        #pragma unroll
        for (int jj = 0; jj < 4; ++jj) {
            int dd = db + jj;
            float acc = 0.f;
            #pragma unroll
            for (int e = 0; e < 16; ++e) acc += out_w[dd * 16 + e] * ys[s * 136 + t * 17 + e];
            outs[(t * 8 + dd) * 17 + s] = acc;   // channel c = t*8+dd
        }
    }
    __syncthreads();

    // ---- coalesced NCHW store + GroupNorm partials (iteration k == group g) ----
    float sg[4], sg2[4];
    #pragma unroll
    for (int k = 0; k < 4; ++k) {
        int i = tid + k * 256;
        int c = i >> 4, j = i & 15;
        float v = outs[c * 17 + j];
        spe_raw[((size_t)b * NC + c) * HW_ + hw0 + j] = v;
        sg[k] = v; sg2[k] = v * v;
    }
    #pragma unroll
    for (int k = 0; k < 4; ++k) {
        #pragma unroll
        for (int o = 1; o < 64; o <<= 1) {
            sg[k]  += __shfl_xor(sg[k], o, 64);
            sg2[k] += __shfl_xor(sg2[k], o, 64);
        }
    }
    if ((tid & 63) == 0) {
        int w = tid >> 6;
        #pragma unroll
        for (int k = 0; k < 4; ++k) { wred[w*8 + k*2] = sg[k]; wred[w*8 + k*2 + 1] = sg2[k]; }
    }
    __syncthreads();
    if (tid < 8)
        part_spe[blockIdx.x * 8 + tid] = wred[tid] + wred[8+tid] + wred[16+tid] + wred[24+tid];
}

// ---------------------------------------------------------------------------
// K5b: reduce GN partials -> (mean, rstd) for 2 branches x 2 b x 4 groups
// ---------------------------------------------------------------------------
__global__ __launch_bounds__(256) void k5b_stats(
    const float* __restrict__ part_spa, const float* __restrict__ part_spe,
    float* __restrict__ stats)
{
    __shared__ float r1[256];
    __shared__ float fin[32];
    const int tid = threadIdx.x;
    const int combo = tid >> 4, sl = tid & 15;      // combo = b*8 + g*2 + st
    const int bb = combo >> 3, g = (combo >> 1) & 3, st = combo & 1;
    float acc = 0.f;
    for (int k = 0; k < 32; ++k)
        acc += part_spa[(bb * 512 + sl * 32 + k) * 8 + g * 2 + st];
    r1[tid] = acc;
    __syncthreads();
    if (tid < 16) { float a = 0.f; for (int k = 0; k < 16; ++k) a += r1[tid*16 + k]; fin[tid] = a; }
    __syncthreads();
    acc = 0.f;
    for (int k = 0; k < 64; ++k)
        acc += part_spe[(bb * 1024 + sl * 64 + k) * 8 + g * 2 + st];
    r1[tid] = acc;
    __syncthreads();
    if (tid < 16) { float a = 0.f; for (int k = 0; k < 16; ++k) a += r1[tid*16 + k]; fin[16 + tid] = a; }
    __syncthreads();
    if (tid < 16) {
        float S  = fin[(tid >> 3) * 16 + (tid & 7) * 2];
        float S2 = fin[(tid >> 3) * 16 + (tid & 7) * 2 + 1];
        const float N = 262144.f;     // 16 channels * 16384 positions
        float mu = S / N;
        float var = S2 / N - mu * mu;
        stats[tid * 2] = mu;
        stats[tid * 2 + 1] = rsqrtf(var + 1e-5f);
    }
}

// ---------------------------------------------------------------------------
// K6: GN-normalize + silu + residual for both branches, softmax fuse, store
// ---------------------------------------------------------------------------
__global__ __launch_bounds__(256) void k6_fuse(
    const float* __restrict__ x, const float* __restrict__ spa_raw,
    const float* __restrict__ spe_raw, const float* __restrict__ stats,
    const float* __restrict__ gwa, const float* __restrict__ gba,
    const float* __restrict__ gwe, const float* __restrict__ gbe,
    const float* __restrict__ fw, float* __restrict__ out)
{
    size_t i4 = (size_t)blockIdx.x * 256 + threadIdx.x;
    size_t base = i4 * 4;
    int b = (int)(base >> 20);
    int rem = (int)(base & 1048575);
    int c = rem >> 14;
    int g = c >> 4;
    int sidx = (b * 4 + g) * 2;
    float ma = stats[sidx],      ra = stats[sidx + 1];
    float me = stats[16 + sidx], re = stats[16 + sidx + 1];
    float wa = gwa[c], ba = gba[c], we = gwe[c], be = gbe[c];
    float f0 = fw[0], f1 = fw[1];
    float mx = fmaxf(f0, f1);
    float e0 = __expf(f0 - mx), e1 = __expf(f1 - mx);
    float inv = 1.f / (e0 + e1);
    float w0 = e0 * inv, w1 = e1 * inv;
    float4 xv = *(const float4*)(x + base);
    float4 av = *(const float4*)(spa_raw + base);
    float4 ev = *(const float4*)(spe_raw + base);
    float xr[4] = {xv.x, xv.y, xv.z, xv.w};
    float ar[4] = {av.x, av.y, av.z, av.w};
    float er[4] = {ev.x, ev.y, ev.z, ev.w};
    float orr[4];
    #pragma unroll
    for (int k = 0; k < 4; ++k) {
        float spa = siluf_((ar[k] - ma) * ra * wa + ba) + xr[k];
        float spe = siluf_((er[k] - me) * re * we + be) + xr[k];
        orr[k] = spa * w0 + spe * w1 + xr[k];
    }
    float4 ov = {orr[0], orr[1], orr[2], orr[3]};
    *(float4*)(out + base) = ov;
}

// ---------------------------------------------------------------------------
extern "C" void kernel_launch(void* const* d_in, const int* in_sizes, int n_in,
                              void* d_out, int out_size, void* d_ws, size_t ws_size,
                              hipStream_t stream)
{
    const float* x      = (const float*)d_in[0];
    const float* a_inw  = (const float*)d_in[1];
    const float* a_cw   = (const float*)d_in[2];
    const float* a_cb   = (const float*)d_in[3];
    const float* a_xp   = (const float*)d_in[4];
    const float* a_dtw  = (const float*)d_in[5];
    const float* a_dtb  = (const float*)d_in[6];
    const float* a_Alog = (const float*)d_in[7];
    const float* a_D    = (const float*)d_in[8];
    const float* a_ow   = (const float*)d_in[9];
    const float* e_inw  = (const float*)d_in[10];
    const float* e_cw   = (const float*)d_in[11];
    const float* e_cb   = (const float*)d_in[12];
    const float* e_xp   = (const float*)d_in[13];
    const float* e_dtw  = (const float*)d_in[14];
    const float* e_dtb  = (const float*)d_in[15];
    const float* e_Alog = (const float*)d_in[16];
    const float* e_D    = (const float*)d_in[17];
    const float* e_ow   = (const float*)d_in[18];
    const float* gwa    = (const float*)d_in[19];
    const float* gba    = (const float*)d_in[20];
    const float* gwe    = (const float*)d_in[21];
    const float* gbe    = (const float*)d_in[22];
    const float* fw     = (const float*)d_in[23];

    float* ws    = (float*)d_ws;
    float* xc    = ws;                    // 32768*128 = 4194304
    float* sz    = xc    + 4194304;       // 4194304
    float* Bm    = sz    + 4194304;       // 524288
    float* Cm    = Bm    + 524288;        // 524288
    float* dtp   = Cm    + 524288;        // 131072
    float* cumA  = dtp   + 131072;        // 2*512*2048 = 2097152
    float* hsum  = cumA  + 2097152;       // 2097152
    float* Hin   = hsum  + 2097152;       // 2097152
    float* spa_r = Hin   + 2097152;       // 2097152
    float* spe_r = spa_r + 2097152;       // 2097152
    float* pspa  = spe_r + 2097152;       // 1024*8
    float* pspe  = pspa  + 8192;          // 2048*8
    float* stats = pspe  + 16384;         // 32

    k1_spatial_pre<<<512, 256, 0, stream>>>(x, a_inw, a_cw, a_cb, a_xp,
                                            xc, sz, dtp, Bm, Cm);
    k2_scan1<<<1024, 256, 0, stream>>>(xc, Bm, dtp, a_dtw, a_dtb, a_Alog,
                                       cumA, hsum);
    k3_combine<<<16, 256, 0, stream>>>(cumA, hsum, Hin);
    k5_spectral<<<2048, 256, 0, stream>>>(x, e_inw, e_cw, e_cb, e_xp, e_dtw, e_dtb,
                                          e_Alog, e_D, e_ow, spe_r, pspe);
    k4_scan2<<<1024, 256, 0, stream>>>(xc, sz, Bm, Cm, dtp, a_dtw, a_dtb, a_Alog,
                                       a_D, Hin, a_ow, spa_r, pspa);
    k5b_stats<<<1, 256, 0, stream>>>(pspa, pspe, stats);
    k6_fuse<<<2048, 256, 0, stream>>>(x, spa_r, spe_r, stats, gwa, gba, gwe, gbe, fw,
                                      (float*)d_out);
}